// Round 21
// baseline (455.248 us; speedup 1.0000x reference)
//
#include <hip/hip_runtime.h>
#include <hip/hip_bf16.h>

#define B_ 8
#define S_ 2048
#define E_ 256
#define FF_ 1024
#define NQ_ 8
#define NC_ 10
#define BS_ (B_*S_)
#define NSPLIT 2
#define KVBLK 32

typedef __bf16 bf16x8 __attribute__((ext_vector_type(8)));
typedef __bf16 bf16x4 __attribute__((ext_vector_type(4)));
typedef float f32x4 __attribute__((ext_vector_type(4)));

#define MFMA16(a,b,c) __builtin_amdgcn_mfma_f32_16x16x32_bf16(a,b,c,0,0,0)

// ---------------- embed + positional encoding ----------------
__global__ __launch_bounds__(256) void k_embed(const int* __restrict__ tokens,
                                               const float* __restrict__ emb,
                                               float* __restrict__ x) {
    int row = blockIdx.x;           // 0..BS_-1
    int e = threadIdx.x;            // 0..255
    int s = row & (S_ - 1);
    int tok = tokens[row];
    int i2 = e & ~1;                // 2*(e/2)
    float d = __expf((float)i2 * (-9.210340371976184f / 256.0f));
    float ang = (float)s * d;
    float pe = (e & 1) ? __cosf(ang) : __sinf(ang);
    x[(size_t)row * E_ + e] = emb[(size_t)tok * E_ + e] + pe;
}

// ---------------- fused q-compute + transpose ----------------
__global__ __launch_bounds__(256) void k_qt(const float* __restrict__ x,
                                            const float* __restrict__ phi_l,
                                            __hip_bfloat16* __restrict__ qbf,
                                            __hip_bfloat16* __restrict__ qT) {
    __shared__ __align__(16) __bf16 tile[64][76];
    int t0 = blockIdx.x * 64, e0 = blockIdx.y * 64, b = blockIdx.z;
    int tid = threadIdx.x;
    float ph[8];
#pragma unroll
    for (int j = 0; j < 8; j++) ph[j] = phi_l[j];
#pragma unroll
    for (int k = 0; k < 2; k++) {
        int idx = k * 256 + tid;
        int r = idx >> 3, hh = idx & 7;           // row, head-slot (8 e each)
        const float* xp = x + ((size_t)b * S_ + t0 + r) * E_ + e0 + hh * 8;
        f32x4 x0 = *(const f32x4*)xp;
        f32x4 x1 = *(const f32x4*)(xp + 4);
        float c[8];
#pragma unroll
        for (int j = 0; j < 4; j++) {
            c[j]     = __cosf(x0[j] + ph[j]);
            c[4 + j] = __cosf(x1[j] + ph[4 + j]);
        }
        float q[8];
        float run = c[0];
#pragma unroll
        for (int i = 1; i < 8; i++) { run *= c[i]; q[i] = run; }
        float o0 = c[1];
#pragma unroll
        for (int i = 2; i < 8; i++) o0 *= c[i];
        q[0] = o0;
        bf16x8 v;
#pragma unroll
        for (int j = 0; j < 8; j++) v[j] = (__bf16)q[j];
        *(bf16x8*)(qbf + ((size_t)b * S_ + t0 + r) * E_ + e0 + hh * 8) = v;
        *(bf16x8*)&tile[r][hh * 8] = v;
    }
    __syncthreads();
#pragma unroll
    for (int k = 0; k < 2; k++) {
        int idx = k * 256 + tid;
        int el = idx >> 3, tc = idx & 7;          // e-local, t-chunk
        bf16x8 v;
#pragma unroll
        for (int j = 0; j < 8; j++) v[j] = tile[tc * 8 + j][el];
        *(bf16x8*)(qT + ((size_t)b * E_ + e0 + el) * S_ + t0 + tc * 8) = v;
    }
}

// ---------------- flash attention: wave-private P, 1 barrier/iter, K+V dbuf via global_load_lds ----------------
// p = exp(s - 44): |s| <= 90.5, diag s_ii >= 0 => no overflow, row-sum >= e^-44.
// Mathematically identical to softmax. 1D grid 512: b = bid&7 (batch->XCD pin).
// Re-partition vs R20: wave = 16 q-rows x full 256 e (was 32q x 128e). P is wave-private
// (lgkmcnt(0) sync, no barrier); ktile+vtile both double-buffered -> ONE barrier/iter,
// with vmcnt(0) covering loads issued a full QK+PV earlier (near-zero stall).
__global__ __launch_bounds__(256, 2) void k_attn(const __hip_bfloat16* __restrict__ qbf,
                                                 const __hip_bfloat16* __restrict__ qT,
                                                 __bf16* __restrict__ pacc,
                                                 float* __restrict__ pl) {
    __shared__ __align__(16) __bf16 ktile[2][KVBLK * 256];  // 2x16KB [kv32][e256], chunk ^= r&7
    __shared__ __align__(16) __bf16 vtile[2][256 * KVBLK];  // 2x16KB [e][kv32], chunk ^= (e>>1)&3
    __shared__ __align__(16) __bf16 plds[4][16][36];        // per-wave P (16q x 32kv + pad)
    const float SCALE = 0.3535533905932738f;                // 1/sqrt(8)
    int bid  = blockIdx.x;
    int b    = bid & 7;                                     // batch == XCD
    int qt   = (bid >> 3) & 31;
    int z    = bid >> 8;
    int tid  = threadIdx.x;
    int wv   = tid >> 6;
    int lane = tid & 63;
    int r16  = lane & 15;
    int kg   = lane >> 4;
    int qrow0 = qt * 64 + wv * 16;                          // this wave's 16 q-rows

    bf16x8 aq[8];
#pragma unroll
    for (int kk = 0; kk < 8; kk++)
        aq[kk] = *(const bf16x8*)(qbf + ((size_t)b * S_ + qrow0 + r16) * E_ + kk * 32 + kg * 8);

    f32x4 acc[16];
#pragma unroll
    for (int cf = 0; cf < 16; cf++) acc[cf] = (f32x4){0.f, 0.f, 0.f, 0.f};
    float lrow[4] = {0.f, 0.f, 0.f, 0.f};

    constexpr int SPAN = S_ / NSPLIT;
    constexpr int NT = SPAN / KVBLK;    // 32
    int k0 = z * SPAN;

    auto issue_k = [&](int kb, int buf) {
#pragma unroll
        for (int c = 0; c < 4; c++) {
            int seg = wv * 4 + c;                       // 16 x 1KB segments (32 rows x 512B)
            int r = seg * 2 + (lane >> 5);
            int ch = lane & 31;
            const __hip_bfloat16* src = qbf + ((size_t)b * S_ + kb + r) * E_ + ((ch ^ (r & 7)) * 8);
            __builtin_amdgcn_global_load_lds((const __attribute__((address_space(1))) void*)src,
                                             (__attribute__((address_space(3))) void*)(&ktile[buf][seg * 512]),
                                             16, 0, 0);
        }
    };
    auto issue_v = [&](int kb, int buf) {
#pragma unroll
        for (int c = 0; c < 4; c++) {
            int seg = wv * 4 + c;                       // 16 x 1KB segments (16 e-rows x 64B each)
            int e = seg * 16 + (lane >> 2);
            int ch = lane & 3;
            const __hip_bfloat16* src = qT + ((size_t)b * E_ + e) * S_ + kb + ((ch ^ ((e >> 1) & 3)) * 8);
            __builtin_amdgcn_global_load_lds((const __attribute__((address_space(1))) void*)src,
                                             (__attribute__((address_space(3))) void*)(&vtile[buf][seg * 512]),
                                             16, 0, 0);
        }
    };

    // prologue: tile 0 into buf 0
    issue_k(k0, 0);
    issue_v(k0, 0);
    asm volatile("s_waitcnt vmcnt(0)" ::: "memory");
    __syncthreads();

    for (int kt = 0; kt < NT; kt++) {
        int cur = kt & 1;
        bool more = (kt + 1 < NT);
        if (more) {                              // issue early: lands under QK+exp+PV
            int kn = k0 + (kt + 1) * KVBLK;
            issue_k(kn, cur ^ 1);
            issue_v(kn, cur ^ 1);
        }
        // ---- QK^T: both kv-halves, this wave's 16 q-rows ----
        f32x4 s0 = (f32x4){0.f,0.f,0.f,0.f}, s1 = (f32x4){0.f,0.f,0.f,0.f};
#pragma unroll
        for (int kk = 0; kk < 8; kk++) {
            int sw = ((kk * 4 + kg) ^ (r16 & 7)) * 8;
            bf16x8 bk0 = *(const bf16x8*)&ktile[cur][r16 * 256 + sw];
            bf16x8 bk1 = *(const bf16x8*)&ktile[cur][(16 + r16) * 256 + sw];
            s0 = MFMA16(aq[kk], bk0, s0);
            s1 = MFMA16(aq[kk], bk1, s1);
        }
        // ---- p = exp(s*SCALE - 44); wave-private P tile ----
#pragma unroll
        for (int i = 0; i < 4; i++) {
            float p0 = __expf(fmaf(s0[i], SCALE, -44.0f));
            float p1 = __expf(fmaf(s1[i], SCALE, -44.0f));
            plds[wv][kg * 4 + i][r16]      = (__bf16)p0;
            plds[wv][kg * 4 + i][16 + r16] = (__bf16)p1;
            lrow[i] += p0 + p1;
        }
        asm volatile("s_waitcnt lgkmcnt(0)" ::: "memory");   // wave-local P visible
        bf16x8 pa = *(const bf16x8*)&plds[wv][r16][kg * 8];
        // ---- PV: full 256-e output ----
#pragma unroll
        for (int cf = 0; cf < 16; cf++) {
            int vrow = cf * 16 + r16;
            bf16x8 bv = *(const bf16x8*)&vtile[cur][vrow * KVBLK + ((kg ^ ((vrow >> 1) & 3)) * 8)];
            acc[cf] = MFMA16(pa, bv, acc[cf]);
        }
        if (more) {
            asm volatile("s_waitcnt vmcnt(0)" ::: "memory");  // t+1 loads landed (issued ~QK+PV ago)
            __syncthreads();                                  // single barrier per iteration
        }
    }

    // ---- epilogue: wave-local l reduce + partial writes (bf16) ----
#pragma unroll
    for (int i = 0; i < 4; i++) {
        lrow[i] += __shfl_xor(lrow[i], 1);
        lrow[i] += __shfl_xor(lrow[i], 2);
        lrow[i] += __shfl_xor(lrow[i], 4);
        lrow[i] += __shfl_xor(lrow[i], 8);
    }
    size_t prow0 = (size_t)z * BS_ + (size_t)b * S_ + qrow0;
    if (r16 == 0) {
#pragma unroll
        for (int i = 0; i < 4; i++)
            pl[prow0 + kg * 4 + i] = lrow[i];
    }
#pragma unroll
    for (int i = 0; i < 4; i++) {
#pragma unroll
        for (int cf = 0; cf < 16; cf++)
            pacc[(prow0 + kg * 4 + i) * E_ + cf * 16 + r16] = (__bf16)acc[cf][i];
    }
}

// ---------------- fused merge (2 bf16 partials) + residual + layernorm ----------------
__global__ __launch_bounds__(256) void k_aln(const __bf16* __restrict__ pacc,
                                             const float* __restrict__ pl,
                                             float* __restrict__ x,
                                             const float* __restrict__ g,
                                             const float* __restrict__ bb) {
    int wv = threadIdx.x >> 6, lane = threadIdx.x & 63;
    size_t row = (size_t)blockIdx.x * 4 + wv;
    float inv = 1.0f / (pl[row] + pl[BS_ + row]);
    bf16x4 a0 = ((const bf16x4*)(pacc + row * E_))[lane];
    bf16x4 a1 = ((const bf16x4*)(pacc + (size_t)BS_ * E_ + row * E_))[lane];
    f32x4 xv = ((const f32x4*)(x + row * E_))[lane];
    f32x4 v;
    float s = 0.f, sq = 0.f;
#pragma unroll
    for (int j = 0; j < 4; j++) {
        v[j] = xv[j] + ((float)a0[j] + (float)a1[j]) * inv;
        s += v[j]; sq += v[j] * v[j];
    }
#pragma unroll
    for (int m = 1; m <= 32; m <<= 1) { s += __shfl_xor(s, m); sq += __shfl_xor(sq, m); }
    float mean = s * (1.f / E_);
    float var = sq * (1.f / E_) - mean * mean;
    float rstd = rsqrtf(var + 1e-5f);
    f32x4 gv = ((const f32x4*)g)[lane];
    f32x4 bv = ((const f32x4*)bb)[lane];
    f32x4 o;
#pragma unroll
    for (int j = 0; j < 4; j++) o[j] = (v[j] - mean) * rstd * gv[j] + bv[j];
    ((f32x4*)(x + row * E_))[lane] = o;
}

// ---------------- W2 transpose to bf16 (tiled): (1024,256) -> (256,1024) ----------------
__global__ __launch_bounds__(256) void k_w2t(const float* __restrict__ W2l,
                                             __hip_bfloat16* __restrict__ w2t) {
    __shared__ __align__(16) __bf16 tile[64][72];
    int k0 = blockIdx.x * 64, e0 = blockIdx.y * 64;
    int tid = threadIdx.x;
#pragma unroll
    for (int half = 0; half < 2; half++) {
        int r  = half * 32 + (tid >> 3);      // k row
        int c8 = (tid & 7) * 8;               // e offset
        f32x4 v0 = *(const f32x4*)(W2l + (size_t)(k0 + r) * E_ + e0 + c8);
        f32x4 v1 = *(const f32x4*)(W2l + (size_t)(k0 + r) * E_ + e0 + c8 + 4);
#pragma unroll
        for (int j = 0; j < 4; j++) { tile[r][c8 + j] = (__bf16)v0[j]; tile[r][c8 + 4 + j] = (__bf16)v1[j]; }
    }
    __syncthreads();
#pragma unroll
    for (int half = 0; half < 2; half++) {
        int e  = half * 32 + (tid >> 3);
        int k8 = (tid & 7) * 8;
        bf16x8 v;
#pragma unroll
        for (int j = 0; j < 8; j++) v[j] = tile[k8 + j][e];
        *(bf16x8*)(w2t + (size_t)(e0 + e) * FF_ + k0 + k8) = v;
    }
}

// ---------------- fused FFN: rank-8 h + GEMM + bias + residual + LN, dbuf 1-barrier/iter ----------------
__global__ __launch_bounds__(256) void k_ffn(const float* __restrict__ x,
                                             const float* __restrict__ theta_l,
                                             const float* __restrict__ W1l,
                                             const float* __restrict__ b1l,
                                             const __hip_bfloat16* __restrict__ w2t,
                                             const float* __restrict__ b2l,
                                             const float* __restrict__ g,
                                             const float* __restrict__ bb) {
    __shared__ __align__(16) __bf16 Bld[2][256 * 64];   // [buf][e][k64] linear (global_load_lds dest)
    __shared__ __align__(16) __bf16 Ald[2][32 * 64];    // [buf][r][k64], chunk ^= r&7
    __shared__ float qmld[32][9];
    __shared__ float reds[32][4][2];
    int tid = threadIdx.x;
    int wv = tid >> 6, lane = tid & 63;
    int r16 = lane & 15, kg = lane >> 4;
    int rbase = blockIdx.x * 32;
    int ebQ = wv * 64;
    const int NT = FF_ / 64;   // 16

    {   // qm[r][i] = cos(x[row][i]) * cos(theta[i])
        int r = tid >> 3, i = tid & 7;
        qmld[r][i] = __cosf(x[(size_t)(rbase + r) * E_ + i]) * __cosf(theta_l[i]);
    }

    f32x4 w[18];   // W1 chunk (16) + b1 chunk (2), all constant-indexed

    auto issue_B = [&](int kt, int buf) {
#pragma unroll
        for (int s = 0; s < 8; s++) {
            int seg = wv * 8 + s;                       // 32 x 1KB segments
            int e = seg * 8 + (lane >> 3);
            int c = lane & 7;
            const __hip_bfloat16* src = w2t + (size_t)e * FF_ + kt * 64 + ((c ^ (e & 7)) * 8);
            __builtin_amdgcn_global_load_lds((const __attribute__((address_space(1))) void*)src,
                                             (__attribute__((address_space(3))) void*)(&Bld[buf][seg * 512]),
                                             16, 0, 0);
        }
    };
    auto load_W1 = [&](int kt) {
        int c = tid & 7;
        int k = kt * 64 + c * 8;
#pragma unroll
        for (int i = 0; i < 8; i++) {
            w[2 * i]     = *(const f32x4*)(W1l + (size_t)i * FF_ + k);
            w[2 * i + 1] = *(const f32x4*)(W1l + (size_t)i * FF_ + k + 4);
        }
        w[16] = *(const f32x4*)(b1l + k);
        w[17] = *(const f32x4*)(b1l + k + 4);
    };
    auto math_h = [&](int buf) {
        int r = tid >> 3, c = tid & 7;
        f32x4 h0 = w[16], h1 = w[17];
#pragma unroll
        for (int i = 0; i < 8; i++) {
            float qv = qmld[r][i];
#pragma unroll
            for (int j = 0; j < 4; j++) {
                h0[j] = fmaf(qv, w[2 * i][j], h0[j]);
                h1[j] = fmaf(qv, w[2 * i + 1][j], h1[j]);
            }
        }
        bf16x8 hv;
#pragma unroll
        for (int j = 0; j < 4; j++) {
            hv[j]     = (__bf16)fmaxf(h0[j], 0.f);
            hv[4 + j] = (__bf16)fmaxf(h1[j], 0.f);
        }
        *(bf16x8*)&Ald[buf][r * 64 + ((c ^ (r & 7)) * 8)] = hv;
    };

    // prologue
    issue_B(0, 0);
    load_W1(0);
    __syncthreads();          // qmld visible; B(0) drained
    math_h(0);
    __syncthreads();          // Ald[0] visible

    f32x4 acc[2][4];
#pragma unroll
    for (int qs = 0; qs < 2; qs++)
#pragma unroll
        for (int cf = 0; cf < 4; cf++) acc[qs][cf] = (f32x4){0.f, 0.f, 0.f, 0.f};

    for (int kt = 0; kt < NT; kt++) {
        int cur = kt & 1;
        bool more = (kt + 1 < NT);
        if (more) {
            issue_B(kt + 1, cur ^ 1);   // in flight across MFMA phase
            load_W1(kt + 1);            // reg prefetch, consumed after MFMA
        }
        bf16x8 aq[2][2];
#pragma unroll
        for (int qs = 0; qs < 2; qs++)
#pragma unroll
            for (int kk = 0; kk < 2; kk++)
                aq[qs][kk] = *(const bf16x8*)&Ald[cur][(qs * 16 + r16) * 64 + (((kk * 4 + kg) ^ (r16 & 7)) * 8)];
#pragma unroll
        for (int cf = 0; cf < 4; cf++) {
            int e = ebQ + cf * 16 + r16;
#pragma unroll
            for (int kk = 0; kk < 2; kk++) {
                bf16x8 bv = *(const bf16x8*)&Bld[cur][e * 64 + (((kk * 4 + kg) ^ (e & 7)) * 8)];
                acc[0][cf] = MFMA16(aq[0][kk], bv, acc[0][cf]);
                acc[1][cf] = MFMA16(aq[1][kk], bv, acc[1][cf]);
            }
        }
        if (more) {
            math_h(cur ^ 1);            // W1 regs already resident
            __syncthreads();            // drains B(kt+1) + Ald writes; guards buf reuse
        }
    }

    // epilogue: bias + residual + layernorm
    float sA[2][4] = {{0.f,0.f,0.f,0.f},{0.f,0.f,0.f,0.f}};
    float sQ[2][4] = {{0.f,0.f,0.f,0.f},{0.f,0.f,0.f,0.f}};
#pragma unroll
    for (int qs = 0; qs < 2; qs++)
#pragma unroll
        for (int cf = 0; cf < 4; cf++) {
            int e = ebQ + cf * 16 + r16;
            float b2v = b2l[e];
#pragma unroll
            for (int i = 0; i < 4; i++) {
                size_t orow = (size_t)rbase + qs * 16 + kg * 4 + i;
                float t = acc[qs][cf][i] + b2v + x[orow * E_ + e];
                acc[qs][cf][i] = t;
                sA[qs][i] += t; sQ[qs][i] += t * t;
            }
        }
#pragma unroll
    for (int qs = 0; qs < 2; qs++)
#pragma unroll
        for (int i = 0; i < 4; i++) {
#pragma unroll
            for (int m = 1; m <= 8; m <<= 1) {
                sA[qs][i] += __shfl_xor(sA[qs][i], m);
                sQ[qs][i] += __shfl_xor(sQ[qs][i], m);
            }
        }
    if (r16 == 0) {
#pragma unroll
        for (int qs = 0; qs < 2; qs++)
#pragma unroll
            for (int i = 0; i < 4; i++) {
                int row = qs * 16 + kg * 4 + i;
                reds[row][wv][0] = sA[qs][i];
                reds[row][wv][1] = sQ[qs][i];
            }
    }
    __syncthreads();
    float mean[2][4], rstd[2][4];
#pragma unroll
    for (int qs = 0; qs < 2; qs++)
#pragma unroll
        for (int i = 0; i < 4; i++) {
            int row = qs * 16 + kg * 4 + i;
            float S = reds[row][0][0] + reds[row][1][0] + reds[row][2][0] + reds[row][3][0];
            float Q = reds[row][0][1] + reds[row][1][1] + reds[row][2][1] + reds[row][3][1];
            mean[qs][i] = S * (1.f / E_);
            float var = Q * (1.f / E_) - mean[qs][i] * mean[qs][i];
            rstd[qs][i] = rsqrtf(var + 1e-5f);
        }
    float* xo = (float*)x;
#pragma unroll
    for (int qs = 0; qs < 2; qs++)
#pragma unroll
        for (int cf = 0; cf < 4; cf++) {
            int e = ebQ + cf * 16 + r16;
            float gv = g[e], bv = bb[e];
#pragma unroll
            for (int i = 0; i < 4; i++) {
                size_t orow = (size_t)rbase + qs * 16 + kg * 4 + i;
                xo[orow * E_ + e] = (acc[qs][cf][i] - mean[qs][i]) * rstd[qs][i] * gv + bv;
            }
        }
}

// ---------------- mean over S (two-stage, deterministic) ----------------
__global__ __launch_bounds__(256) void k_mean(const float* __restrict__ x, float* __restrict__ psum) {
    int c = blockIdx.x, b = blockIdx.y, e = threadIdx.x;
    float s = 0.f;
    size_t base = ((size_t)b * S_ + c * 128) * E_ + e;
    for (int r = 0; r < 128; r++) s += x[base + (size_t)r * E_];
    psum[(c * 8 + b) * E_ + e] = s;
}

__global__ __launch_bounds__(256) void k_mean2(const float* __restrict__ psum, float* __restrict__ xmean) {
    int idx = blockIdx.x * 256 + threadIdx.x;   // 0..2047 -> (b,e)
    int b = idx >> 8, e = idx & 255;
    float s = 0.f;
    for (int c = 0; c < 16; c++) s += psum[(c * 8 + b) * E_ + e];
    xmean[idx] = s * (1.f / S_);
}

// ---------------- classifier ----------------
__global__ __launch_bounds__(128) void k_cls(const float* __restrict__ xmean,
                                             const float* __restrict__ Wc,
                                             const float* __restrict__ bc,
                                             float* __restrict__ outp) {
    int t = threadIdx.x;
    if (t >= B_ * NC_) return;
    int b = t / NC_, c = t % NC_;
    float s = bc[c];
    for (int e = 0; e < E_; e++) s += xmean[b * E_ + e] * Wc[e * NC_ + c];
    outp[t] = s;
}

extern "C" void kernel_launch(void* const* d_in, const int* in_sizes, int n_in,
                              void* d_out, int out_size, void* d_ws, size_t ws_size,
                              hipStream_t stream) {
    (void)in_sizes; (void)n_in; (void)out_size; (void)ws_size;
    const int*   tokens = (const int*)d_in[0];
    const float* emb    = (const float*)d_in[1];
    const float* phi    = (const float*)d_in[2];
    const float* theta  = (const float*)d_in[3];
    const float* W1     = (const float*)d_in[4];
    const float* b1     = (const float*)d_in[5];
    const float* W2     = (const float*)d_in[6];
    const float* b2     = (const float*)d_in[7];
    const float* g1     = (const float*)d_in[8];
    const float* beta1  = (const float*)d_in[9];
    const float* g2     = (const float*)d_in[10];
    const float* beta2  = (const float*)d_in[11];
    const float* Wc     = (const float*)d_in[12];
    const float* bc     = (const float*)d_in[13];
    float* outp = (float*)d_out;

    // workspace layout (NSPLIT=2; w2t holds all 4 layers; pacc bf16)
    float* xbuf = (float*)d_ws;                                        // BS_*E_ f32
    __hip_bfloat16* qbf = (__hip_bfloat16*)(xbuf + (size_t)BS_ * E_);  // BS_*E_ bf16
    __hip_bfloat16* qT  = qbf + (size_t)BS_ * E_;                      // BS_*E_ bf16
    __hip_bfloat16* w2t = qT + (size_t)BS_ * E_;                       // 4*E_*FF_ bf16
    float* psum  = (float*)(w2t + (size_t)4 * E_ * FF_);               // 16*8*E_ f32
    float* xmean = psum + 16 * 8 * E_;                                 // B_*E_ f32
    float* pl    = xmean + B_ * E_;                                    // NSPLIT*BS_ f32
    __bf16* pacc = (__bf16*)(pl + (size_t)NSPLIT * BS_);               // NSPLIT*BS_*E_ bf16

    k_embed<<<BS_, 256, 0, stream>>>(tokens, emb, xbuf);
    for (int l = 0; l < 4; l++)      // layer-static: hoisted out of the layer loop
        k_w2t<<<dim3(FF_ / 64, E_ / 64), 256, 0, stream>>>(W2 + (size_t)l * FF_ * E_,
                                                           w2t + (size_t)l * E_ * FF_);

    for (int l = 0; l < 4; l++) {
        k_qt<<<dim3(S_ / 64, E_ / 64, B_), 256, 0, stream>>>(xbuf, phi + l * NQ_, qbf, qT);
        k_attn<<<(S_ / 64) * B_ * NSPLIT, 256, 0, stream>>>(qbf, qT, pacc, pl);
        k_aln<<<BS_ / 4, 256, 0, stream>>>(pacc, pl, xbuf, g1 + l * E_, beta1 + l * E_);
        k_ffn<<<BS_ / 32, 256, 0, stream>>>(xbuf, theta + l * NQ_,
                                            W1 + (size_t)l * NQ_ * FF_, b1 + (size_t)l * FF_,
                                            w2t + (size_t)l * E_ * FF_, b2 + (size_t)l * E_,
                                            g2 + l * E_, beta2 + l * E_);
    }

    k_mean<<<dim3(16, B_), 256, 0, stream>>>(xbuf, psum);
    k_mean2<<<8, 256, 0, stream>>>(psum, xmean);
    k_cls<<<1, 128, 0, stream>>>(xmean, Wc, bc, outp);
}

// Round 22
// 441.469 us; speedup vs baseline: 1.0312x; 1.0312x over previous
//
#include <hip/hip_runtime.h>
#include <hip/hip_bf16.h>

#define B_ 8
#define S_ 2048
#define E_ 256
#define FF_ 1024
#define NQ_ 8
#define NC_ 10
#define BS_ (B_*S_)
#define NSPLIT 2
#define KVBLK 32

typedef __bf16 bf16x8 __attribute__((ext_vector_type(8)));
typedef __bf16 bf16x4 __attribute__((ext_vector_type(4)));
typedef float f32x4 __attribute__((ext_vector_type(4)));

#define MFMA16(a,b,c) __builtin_amdgcn_mfma_f32_16x16x32_bf16(a,b,c,0,0,0)

// ---------------- embed + positional encoding ----------------
__global__ __launch_bounds__(256) void k_embed(const int* __restrict__ tokens,
                                               const float* __restrict__ emb,
                                               float* __restrict__ x) {
    int row = blockIdx.x;           // 0..BS_-1
    int e = threadIdx.x;            // 0..255
    int s = row & (S_ - 1);
    int tok = tokens[row];
    int i2 = e & ~1;                // 2*(e/2)
    float d = __expf((float)i2 * (-9.210340371976184f / 256.0f));
    float ang = (float)s * d;
    float pe = (e & 1) ? __cosf(ang) : __sinf(ang);
    x[(size_t)row * E_ + e] = emb[(size_t)tok * E_ + e] + pe;
}

// ---------------- fused q-compute + transpose ----------------
__global__ __launch_bounds__(256) void k_qt(const float* __restrict__ x,
                                            const float* __restrict__ phi_l,
                                            __hip_bfloat16* __restrict__ qbf,
                                            __hip_bfloat16* __restrict__ qT) {
    __shared__ __align__(16) __bf16 tile[64][76];
    int t0 = blockIdx.x * 64, e0 = blockIdx.y * 64, b = blockIdx.z;
    int tid = threadIdx.x;
    float ph[8];
#pragma unroll
    for (int j = 0; j < 8; j++) ph[j] = phi_l[j];
#pragma unroll
    for (int k = 0; k < 2; k++) {
        int idx = k * 256 + tid;
        int r = idx >> 3, hh = idx & 7;           // row, head-slot (8 e each)
        const float* xp = x + ((size_t)b * S_ + t0 + r) * E_ + e0 + hh * 8;
        f32x4 x0 = *(const f32x4*)xp;
        f32x4 x1 = *(const f32x4*)(xp + 4);
        float c[8];
#pragma unroll
        for (int j = 0; j < 4; j++) {
            c[j]     = __cosf(x0[j] + ph[j]);
            c[4 + j] = __cosf(x1[j] + ph[4 + j]);
        }
        float q[8];
        float run = c[0];
#pragma unroll
        for (int i = 1; i < 8; i++) { run *= c[i]; q[i] = run; }
        float o0 = c[1];
#pragma unroll
        for (int i = 2; i < 8; i++) o0 *= c[i];
        q[0] = o0;
        bf16x8 v;
#pragma unroll
        for (int j = 0; j < 8; j++) v[j] = (__bf16)q[j];
        *(bf16x8*)(qbf + ((size_t)b * S_ + t0 + r) * E_ + e0 + hh * 8) = v;
        *(bf16x8*)&tile[r][hh * 8] = v;
    }
    __syncthreads();
#pragma unroll
    for (int k = 0; k < 2; k++) {
        int idx = k * 256 + tid;
        int el = idx >> 3, tc = idx & 7;          // e-local, t-chunk
        bf16x8 v;
#pragma unroll
        for (int j = 0; j < 8; j++) v[j] = tile[tc * 8 + j][el];
        *(bf16x8*)(qT + ((size_t)b * E_ + e0 + el) * S_ + t0 + tc * 8) = v;
    }
}

// ---------------- flash attention: Wq=32, KVBLK=32, K+V via global_load_lds, vtile dbuf ----------------
// p = exp(s - 44): |s| <= 90.5, diag s_ii >= 0 => no overflow, row-sum >= e^-44.
// Mathematically identical to softmax. 1D grid 512: b = bid&7 (batch->XCD pin).
// R20-measured best (58us): shared-P 32qx128e partition, 2 barriers/iter.
// Refuted alternatives: occupancy-4blk (R13), V-from-L2 (R17), setprio (R18),
// KVBLK=64 (R14 ~neutral), wave-private-P 1-barrier (R21: +4us, 2x conflicts).
__global__ __launch_bounds__(256, 2) void k_attn(const __hip_bfloat16* __restrict__ qbf,
                                                 const __hip_bfloat16* __restrict__ qT,
                                                 __bf16* __restrict__ pacc,
                                                 float* __restrict__ pl) {
    __shared__ __align__(16) __bf16 ktile[KVBLK * 256];     // 16KB [kv32][e256], chunk ^= r&7
    __shared__ __align__(16) __bf16 vtile[2][256 * KVBLK];  // 2x16KB [e][kv32], chunk ^= (e>>1)&3
    __shared__ __align__(16) __bf16 plds[2][32][36];        // 4.6KB [rg][q32][kv32+4] (18-word rows)
    __shared__ float redl[2][32][2];
    const float SCALE = 0.3535533905932738f;                // 1/sqrt(8)
    int bid  = blockIdx.x;
    int b    = bid & 7;                                     // batch == XCD
    int qt   = (bid >> 3) & 31;
    int z    = bid >> 8;
    int tid  = threadIdx.x;
    int wv   = tid >> 6;
    int lane = tid & 63;
    int r16  = lane & 15;
    int kg   = lane >> 4;
    int rg   = wv >> 1, eh = wv & 1;
    int qrow0 = qt * 64 + rg * 32;
    int ebase = eh * 128;

    bf16x8 aq[2][8];
#pragma unroll
    for (int qs = 0; qs < 2; qs++)
#pragma unroll
        for (int kk = 0; kk < 8; kk++)
            aq[qs][kk] = *(const bf16x8*)(qbf + ((size_t)b * S_ + qrow0 + qs * 16 + r16) * E_ + kk * 32 + kg * 8);

    f32x4 acc0[8], acc1[8];
#pragma unroll
    for (int cf = 0; cf < 8; cf++) { acc0[cf] = (f32x4){0.f,0.f,0.f,0.f}; acc1[cf] = (f32x4){0.f,0.f,0.f,0.f}; }
    float lrow0[4] = {0.f,0.f,0.f,0.f}, lrow1[4] = {0.f,0.f,0.f,0.f};

    constexpr int SPAN = S_ / NSPLIT;
    constexpr int NT = SPAN / KVBLK;    // 32
    int k0 = z * SPAN;

    auto issue_k = [&](int kb) {
#pragma unroll
        for (int c = 0; c < 4; c++) {
            int seg = wv * 4 + c;                       // 16 x 1KB segments (32 rows x 512B)
            int r = seg * 2 + (lane >> 5);
            int ch = lane & 31;
            const __hip_bfloat16* src = qbf + ((size_t)b * S_ + kb + r) * E_ + ((ch ^ (r & 7)) * 8);
            __builtin_amdgcn_global_load_lds((const __attribute__((address_space(1))) void*)src,
                                             (__attribute__((address_space(3))) void*)(ktile + seg * 512),
                                             16, 0, 0);
        }
    };
    auto issue_v = [&](int kb, int buf) {
#pragma unroll
        for (int c = 0; c < 4; c++) {
            int seg = wv * 4 + c;                       // 16 x 1KB segments (16 e-rows x 64B each)
            int e = seg * 16 + (lane >> 2);
            int ch = lane & 3;
            const __hip_bfloat16* src = qT + ((size_t)b * E_ + e) * S_ + kb + ((ch ^ ((e >> 1) & 3)) * 8);
            __builtin_amdgcn_global_load_lds((const __attribute__((address_space(1))) void*)src,
                                             (__attribute__((address_space(3))) void*)(&vtile[buf][seg * 512]),
                                             16, 0, 0);
        }
    };

    // prologue: tile 0
    issue_k(k0);
    issue_v(k0, 0);
    asm volatile("s_waitcnt vmcnt(0)" ::: "memory");
    __syncthreads();

    for (int kt = 0; kt < NT; kt++) {
        int vcur = kt & 1;
        // ---- QK^T: this wave's kv-half [eh*16, eh*16+16) ----
        f32x4 s0 = (f32x4){0.f,0.f,0.f,0.f}, s1 = (f32x4){0.f,0.f,0.f,0.f};
#pragma unroll
        for (int kk = 0; kk < 8; kk++) {
            bf16x8 bk = *(const bf16x8*)&ktile[(eh * 16 + r16) * 256 + (((kk * 4 + kg) ^ (r16 & 7)) * 8)];
            s0 = MFMA16(aq[0][kk], bk, s0);
            s1 = MFMA16(aq[1][kk], bk, s1);
        }
#pragma unroll
        for (int i = 0; i < 4; i++) {
            float p0 = __expf(fmaf(s0[i], SCALE, -44.0f));
            float p1 = __expf(fmaf(s1[i], SCALE, -44.0f));
            plds[rg][kg * 4 + i][eh * 16 + r16]      = (__bf16)p0;
            plds[rg][16 + kg * 4 + i][eh * 16 + r16] = (__bf16)p1;
            lrow0[i] += p0;
            lrow1[i] += p1;
        }
        __syncthreads();                         // B2: P complete; ktile/vtile[vcur^1] reads done
        bool more = (kt + 1 < NT);
        if (more) {                              // async into ktile + vtile[vcur^1]; lands under PV
            int kn = k0 + (kt + 1) * KVBLK;
            issue_k(kn);
            issue_v(kn, vcur ^ 1);
        }
        // ---- PV ----
        bf16x8 pa0 = *(const bf16x8*)&plds[rg][r16][kg * 8];
        bf16x8 pa1 = *(const bf16x8*)&plds[rg][16 + r16][kg * 8];
#pragma unroll
        for (int cf = 0; cf < 8; cf++) {
            int vrow = ebase + cf * 16 + r16;
            bf16x8 bv = *(const bf16x8*)&vtile[vcur][vrow * KVBLK + ((kg ^ ((vrow >> 1) & 3)) * 8)];
            acc0[cf] = MFMA16(pa0, bv, acc0[cf]);
            acc1[cf] = MFMA16(pa1, bv, acc1[cf]);
        }
        if (more) {
            asm volatile("s_waitcnt vmcnt(0)" ::: "memory");
            __syncthreads();                     // B1: all waves' loads landed
        }
    }

    // ---- epilogue: l totals then partial writes (bf16) ----
#pragma unroll
    for (int i = 0; i < 4; i++) {
#pragma unroll
        for (int m = 1; m <= 8; m <<= 1) {
            lrow0[i] += __shfl_xor(lrow0[i], m);
            lrow1[i] += __shfl_xor(lrow1[i], m);
        }
    }
    if (r16 == 0) {
#pragma unroll
        for (int i = 0; i < 4; i++) {
            redl[rg][kg * 4 + i][eh]      = lrow0[i];
            redl[rg][16 + kg * 4 + i][eh] = lrow1[i];
        }
    }
    __syncthreads();
    size_t prow0 = (size_t)z * BS_ + (size_t)b * S_ + qrow0;
    if (eh == 0 && r16 == 0) {
#pragma unroll
        for (int i = 0; i < 4; i++) {
            int q = kg * 4 + i;
            pl[prow0 + q]      = redl[rg][q][0] + redl[rg][q][1];
            pl[prow0 + 16 + q] = redl[rg][16 + q][0] + redl[rg][16 + q][1];
        }
    }
#pragma unroll
    for (int i = 0; i < 4; i++) {
#pragma unroll
        for (int cf = 0; cf < 8; cf++) {
            pacc[(prow0 + kg * 4 + i) * E_ + ebase + cf * 16 + r16]      = (__bf16)acc0[cf][i];
            pacc[(prow0 + 16 + kg * 4 + i) * E_ + ebase + cf * 16 + r16] = (__bf16)acc1[cf][i];
        }
    }
}

// ---------------- fused merge (2 bf16 partials) + residual + layernorm ----------------
__global__ __launch_bounds__(256) void k_aln(const __bf16* __restrict__ pacc,
                                             const float* __restrict__ pl,
                                             float* __restrict__ x,
                                             const float* __restrict__ g,
                                             const float* __restrict__ bb) {
    int wv = threadIdx.x >> 6, lane = threadIdx.x & 63;
    size_t row = (size_t)blockIdx.x * 4 + wv;
    float inv = 1.0f / (pl[row] + pl[BS_ + row]);
    bf16x4 a0 = ((const bf16x4*)(pacc + row * E_))[lane];
    bf16x4 a1 = ((const bf16x4*)(pacc + (size_t)BS_ * E_ + row * E_))[lane];
    f32x4 xv = ((const f32x4*)(x + row * E_))[lane];
    f32x4 v;
    float s = 0.f, sq = 0.f;
#pragma unroll
    for (int j = 0; j < 4; j++) {
        v[j] = xv[j] + ((float)a0[j] + (float)a1[j]) * inv;
        s += v[j]; sq += v[j] * v[j];
    }
#pragma unroll
    for (int m = 1; m <= 32; m <<= 1) { s += __shfl_xor(s, m); sq += __shfl_xor(sq, m); }
    float mean = s * (1.f / E_);
    float var = sq * (1.f / E_) - mean * mean;
    float rstd = rsqrtf(var + 1e-5f);
    f32x4 gv = ((const f32x4*)g)[lane];
    f32x4 bv = ((const f32x4*)bb)[lane];
    f32x4 o;
#pragma unroll
    for (int j = 0; j < 4; j++) o[j] = (v[j] - mean) * rstd * gv[j] + bv[j];
    ((f32x4*)(x + row * E_))[lane] = o;
}

// ---------------- W2 transpose to bf16 (tiled): (1024,256) -> (256,1024) ----------------
__global__ __launch_bounds__(256) void k_w2t(const float* __restrict__ W2l,
                                             __hip_bfloat16* __restrict__ w2t) {
    __shared__ __align__(16) __bf16 tile[64][72];
    int k0 = blockIdx.x * 64, e0 = blockIdx.y * 64;
    int tid = threadIdx.x;
#pragma unroll
    for (int half = 0; half < 2; half++) {
        int r  = half * 32 + (tid >> 3);      // k row
        int c8 = (tid & 7) * 8;               // e offset
        f32x4 v0 = *(const f32x4*)(W2l + (size_t)(k0 + r) * E_ + e0 + c8);
        f32x4 v1 = *(const f32x4*)(W2l + (size_t)(k0 + r) * E_ + e0 + c8 + 4);
#pragma unroll
        for (int j = 0; j < 4; j++) { tile[r][c8 + j] = (__bf16)v0[j]; tile[r][c8 + 4 + j] = (__bf16)v1[j]; }
    }
    __syncthreads();
#pragma unroll
    for (int half = 0; half < 2; half++) {
        int e  = half * 32 + (tid >> 3);
        int k8 = (tid & 7) * 8;
        bf16x8 v;
#pragma unroll
        for (int j = 0; j < 8; j++) v[j] = tile[k8 + j][e];
        *(bf16x8*)(w2t + (size_t)(e0 + e) * FF_ + k0 + k8) = v;
    }
}

// ---------------- fused FFN: rank-8 h + GEMM + bias + residual + LN, dbuf 1-barrier/iter ----------------
__global__ __launch_bounds__(256) void k_ffn(const float* __restrict__ x,
                                             const float* __restrict__ theta_l,
                                             const float* __restrict__ W1l,
                                             const float* __restrict__ b1l,
                                             const __hip_bfloat16* __restrict__ w2t,
                                             const float* __restrict__ b2l,
                                             const float* __restrict__ g,
                                             const float* __restrict__ bb) {
    __shared__ __align__(16) __bf16 Bld[2][256 * 64];   // [buf][e][k64] linear (global_load_lds dest)
    __shared__ __align__(16) __bf16 Ald[2][32 * 64];    // [buf][r][k64], chunk ^= r&7
    __shared__ float qmld[32][9];
    __shared__ float reds[32][4][2];
    int tid = threadIdx.x;
    int wv = tid >> 6, lane = tid & 63;
    int r16 = lane & 15, kg = lane >> 4;
    int rbase = blockIdx.x * 32;
    int ebQ = wv * 64;
    const int NT = FF_ / 64;   // 16

    {   // qm[r][i] = cos(x[row][i]) * cos(theta[i])
        int r = tid >> 3, i = tid & 7;
        qmld[r][i] = __cosf(x[(size_t)(rbase + r) * E_ + i]) * __cosf(theta_l[i]);
    }

    f32x4 w[18];   // W1 chunk (16) + b1 chunk (2), all constant-indexed

    auto issue_B = [&](int kt, int buf) {
#pragma unroll
        for (int s = 0; s < 8; s++) {
            int seg = wv * 8 + s;                       // 32 x 1KB segments
            int e = seg * 8 + (lane >> 3);
            int c = lane & 7;
            const __hip_bfloat16* src = w2t + (size_t)e * FF_ + kt * 64 + ((c ^ (e & 7)) * 8);
            __builtin_amdgcn_global_load_lds((const __attribute__((address_space(1))) void*)src,
                                             (__attribute__((address_space(3))) void*)(&Bld[buf][seg * 512]),
                                             16, 0, 0);
        }
    };
    auto load_W1 = [&](int kt) {
        int c = tid & 7;
        int k = kt * 64 + c * 8;
#pragma unroll
        for (int i = 0; i < 8; i++) {
            w[2 * i]     = *(const f32x4*)(W1l + (size_t)i * FF_ + k);
            w[2 * i + 1] = *(const f32x4*)(W1l + (size_t)i * FF_ + k + 4);
        }
        w[16] = *(const f32x4*)(b1l + k);
        w[17] = *(const f32x4*)(b1l + k + 4);
    };
    auto math_h = [&](int buf) {
        int r = tid >> 3, c = tid & 7;
        f32x4 h0 = w[16], h1 = w[17];
#pragma unroll
        for (int i = 0; i < 8; i++) {
            float qv = qmld[r][i];
#pragma unroll
            for (int j = 0; j < 4; j++) {
                h0[j] = fmaf(qv, w[2 * i][j], h0[j]);
                h1[j] = fmaf(qv, w[2 * i + 1][j], h1[j]);
            }
        }
        bf16x8 hv;
#pragma unroll
        for (int j = 0; j < 4; j++) {
            hv[j]     = (__bf16)fmaxf(h0[j], 0.f);
            hv[4 + j] = (__bf16)fmaxf(h1[j], 0.f);
        }
        *(bf16x8*)&Ald[buf][r * 64 + ((c ^ (r & 7)) * 8)] = hv;
    };

    // prologue
    issue_B(0, 0);
    load_W1(0);
    __syncthreads();          // qmld visible; B(0) drained
    math_h(0);
    __syncthreads();          // Ald[0] visible

    f32x4 acc[2][4];
#pragma unroll
    for (int qs = 0; qs < 2; qs++)
#pragma unroll
        for (int cf = 0; cf < 4; cf++) acc[qs][cf] = (f32x4){0.f, 0.f, 0.f, 0.f};

    for (int kt = 0; kt < NT; kt++) {
        int cur = kt & 1;
        bool more = (kt + 1 < NT);
        if (more) {
            issue_B(kt + 1, cur ^ 1);   // in flight across MFMA phase
            load_W1(kt + 1);            // reg prefetch, consumed after MFMA
        }
        bf16x8 aq[2][2];
#pragma unroll
        for (int qs = 0; qs < 2; qs++)
#pragma unroll
            for (int kk = 0; kk < 2; kk++)
                aq[qs][kk] = *(const bf16x8*)&Ald[cur][(qs * 16 + r16) * 64 + (((kk * 4 + kg) ^ (r16 & 7)) * 8)];
#pragma unroll
        for (int cf = 0; cf < 4; cf++) {
            int e = ebQ + cf * 16 + r16;
#pragma unroll
            for (int kk = 0; kk < 2; kk++) {
                bf16x8 bv = *(const bf16x8*)&Bld[cur][e * 64 + (((kk * 4 + kg) ^ (e & 7)) * 8)];
                acc[0][cf] = MFMA16(aq[0][kk], bv, acc[0][cf]);
                acc[1][cf] = MFMA16(aq[1][kk], bv, acc[1][cf]);
            }
        }
        if (more) {
            math_h(cur ^ 1);            // W1 regs already resident
            __syncthreads();            // drains B(kt+1) + Ald writes; guards buf reuse
        }
    }

    // epilogue: bias + residual + layernorm
    float sA[2][4] = {{0.f,0.f,0.f,0.f},{0.f,0.f,0.f,0.f}};
    float sQ[2][4] = {{0.f,0.f,0.f,0.f},{0.f,0.f,0.f,0.f}};
#pragma unroll
    for (int qs = 0; qs < 2; qs++)
#pragma unroll
        for (int cf = 0; cf < 4; cf++) {
            int e = ebQ + cf * 16 + r16;
            float b2v = b2l[e];
#pragma unroll
            for (int i = 0; i < 4; i++) {
                size_t orow = (size_t)rbase + qs * 16 + kg * 4 + i;
                float t = acc[qs][cf][i] + b2v + x[orow * E_ + e];
                acc[qs][cf][i] = t;
                sA[qs][i] += t; sQ[qs][i] += t * t;
            }
        }
#pragma unroll
    for (int qs = 0; qs < 2; qs++)
#pragma unroll
        for (int i = 0; i < 4; i++) {
#pragma unroll
            for (int m = 1; m <= 8; m <<= 1) {
                sA[qs][i] += __shfl_xor(sA[qs][i], m);
                sQ[qs][i] += __shfl_xor(sQ[qs][i], m);
            }
        }
    if (r16 == 0) {
#pragma unroll
        for (int qs = 0; qs < 2; qs++)
#pragma unroll
            for (int i = 0; i < 4; i++) {
                int row = qs * 16 + kg * 4 + i;
                reds[row][wv][0] = sA[qs][i];
                reds[row][wv][1] = sQ[qs][i];
            }
    }
    __syncthreads();
    float mean[2][4], rstd[2][4];
#pragma unroll
    for (int qs = 0; qs < 2; qs++)
#pragma unroll
        for (int i = 0; i < 4; i++) {
            int row = qs * 16 + kg * 4 + i;
            float S = reds[row][0][0] + reds[row][1][0] + reds[row][2][0] + reds[row][3][0];
            float Q = reds[row][0][1] + reds[row][1][1] + reds[row][2][1] + reds[row][3][1];
            mean[qs][i] = S * (1.f / E_);
            float var = Q * (1.f / E_) - mean[qs][i] * mean[qs][i];
            rstd[qs][i] = rsqrtf(var + 1e-5f);
        }
    float* xo = (float*)x;
#pragma unroll
    for (int qs = 0; qs < 2; qs++)
#pragma unroll
        for (int cf = 0; cf < 4; cf++) {
            int e = ebQ + cf * 16 + r16;
            float gv = g[e], bv = bb[e];
#pragma unroll
            for (int i = 0; i < 4; i++) {
                size_t orow = (size_t)rbase + qs * 16 + kg * 4 + i;
                xo[orow * E_ + e] = (acc[qs][cf][i] - mean[qs][i]) * rstd[qs][i] * gv + bv;
            }
        }
}

// ---------------- mean over S (two-stage, deterministic) ----------------
__global__ __launch_bounds__(256) void k_mean(const float* __restrict__ x, float* __restrict__ psum) {
    int c = blockIdx.x, b = blockIdx.y, e = threadIdx.x;
    float s = 0.f;
    size_t base = ((size_t)b * S_ + c * 128) * E_ + e;
    for (int r = 0; r < 128; r++) s += x[base + (size_t)r * E_];
    psum[(c * 8 + b) * E_ + e] = s;
}

__global__ __launch_bounds__(256) void k_mean2(const float* __restrict__ psum, float* __restrict__ xmean) {
    int idx = blockIdx.x * 256 + threadIdx.x;   // 0..2047 -> (b,e)
    int b = idx >> 8, e = idx & 255;
    float s = 0.f;
    for (int c = 0; c < 16; c++) s += psum[(c * 8 + b) * E_ + e];
    xmean[idx] = s * (1.f / S_);
}

// ---------------- classifier ----------------
__global__ __launch_bounds__(128) void k_cls(const float* __restrict__ xmean,
                                             const float* __restrict__ Wc,
                                             const float* __restrict__ bc,
                                             float* __restrict__ outp) {
    int t = threadIdx.x;
    if (t >= B_ * NC_) return;
    int b = t / NC_, c = t % NC_;
    float s = bc[c];
    for (int e = 0; e < E_; e++) s += xmean[b * E_ + e] * Wc[e * NC_ + c];
    outp[t] = s;
}

extern "C" void kernel_launch(void* const* d_in, const int* in_sizes, int n_in,
                              void* d_out, int out_size, void* d_ws, size_t ws_size,
                              hipStream_t stream) {
    (void)in_sizes; (void)n_in; (void)out_size; (void)ws_size;
    const int*   tokens = (const int*)d_in[0];
    const float* emb    = (const float*)d_in[1];
    const float* phi    = (const float*)d_in[2];
    const float* theta  = (const float*)d_in[3];
    const float* W1     = (const float*)d_in[4];
    const float* b1     = (const float*)d_in[5];
    const float* W2     = (const float*)d_in[6];
    const float* b2     = (const float*)d_in[7];
    const float* g1     = (const float*)d_in[8];
    const float* beta1  = (const float*)d_in[9];
    const float* g2     = (const float*)d_in[10];
    const float* beta2  = (const float*)d_in[11];
    const float* Wc     = (const float*)d_in[12];
    const float* bc     = (const float*)d_in[13];
    float* outp = (float*)d_out;

    // workspace layout (NSPLIT=2; w2t holds all 4 layers; pacc bf16)
    float* xbuf = (float*)d_ws;                                        // BS_*E_ f32
    __hip_bfloat16* qbf = (__hip_bfloat16*)(xbuf + (size_t)BS_ * E_);  // BS_*E_ bf16
    __hip_bfloat16* qT  = qbf + (size_t)BS_ * E_;                      // BS_*E_ bf16
    __hip_bfloat16* w2t = qT + (size_t)BS_ * E_;                       // 4*E_*FF_ bf16
    float* psum  = (float*)(w2t + (size_t)4 * E_ * FF_);               // 16*8*E_ f32
    float* xmean = psum + 16 * 8 * E_;                                 // B_*E_ f32
    float* pl    = xmean + B_ * E_;                                    // NSPLIT*BS_ f32
    __bf16* pacc = (__bf16*)(pl + (size_t)NSPLIT * BS_);               // NSPLIT*BS_*E_ bf16

    k_embed<<<BS_, 256, 0, stream>>>(tokens, emb, xbuf);
    for (int l = 0; l < 4; l++)      // layer-static: hoisted out of the layer loop
        k_w2t<<<dim3(FF_ / 64, E_ / 64), 256, 0, stream>>>(W2 + (size_t)l * FF_ * E_,
                                                           w2t + (size_t)l * E_ * FF_);

    for (int l = 0; l < 4; l++) {
        k_qt<<<dim3(S_ / 64, E_ / 64, B_), 256, 0, stream>>>(xbuf, phi + l * NQ_, qbf, qT);
        k_attn<<<(S_ / 64) * B_ * NSPLIT, 256, 0, stream>>>(qbf, qT, pacc, pl);
        k_aln<<<BS_ / 4, 256, 0, stream>>>(pacc, pl, xbuf, g1 + l * E_, beta1 + l * E_);
        k_ffn<<<BS_ / 32, 256, 0, stream>>>(xbuf, theta + l * NQ_,
                                            W1 + (size_t)l * NQ_ * FF_, b1 + (size_t)l * FF_,
                                            w2t + (size_t)l * E_ * FF_, b2 + (size_t)l * E_,
                                            g2 + l * E_, beta2 + l * E_);
    }

    k_mean<<<dim3(16, B_), 256, 0, stream>>>(xbuf, psum);
    k_mean2<<<8, 256, 0, stream>>>(psum, xmean);
    k_cls<<<1, 128, 0, stream>>>(xmean, Wc, bc, outp);
}

// Round 23
// 425.657 us; speedup vs baseline: 1.0695x; 1.0371x over previous
//
#include <hip/hip_runtime.h>
#include <hip/hip_bf16.h>

#define B_ 8
#define S_ 2048
#define E_ 256
#define FF_ 1024
#define NQ_ 8
#define NC_ 10
#define BS_ (B_*S_)
#define NSPLIT 2
#define KVBLK 32

typedef __bf16 bf16x8 __attribute__((ext_vector_type(8)));
typedef __bf16 bf16x4 __attribute__((ext_vector_type(4)));
typedef float f32x4 __attribute__((ext_vector_type(4)));

#define MFMA16(a,b,c) __builtin_amdgcn_mfma_f32_16x16x32_bf16(a,b,c,0,0,0)

// ---------------- embed + positional encoding (bf16 residual stream) ----------------
__global__ __launch_bounds__(256) void k_embed(const int* __restrict__ tokens,
                                               const float* __restrict__ emb,
                                               __bf16* __restrict__ x) {
    int row = blockIdx.x;           // 0..BS_-1
    int e = threadIdx.x;            // 0..255
    int s = row & (S_ - 1);
    int tok = tokens[row];
    int i2 = e & ~1;                // 2*(e/2)
    float d = __expf((float)i2 * (-9.210340371976184f / 256.0f));
    float ang = (float)s * d;
    float pe = (e & 1) ? __cosf(ang) : __sinf(ang);
    x[(size_t)row * E_ + e] = (__bf16)(emb[(size_t)tok * E_ + e] + pe);
}

// ---------------- fused q-compute + transpose (reads bf16 x) ----------------
__global__ __launch_bounds__(256) void k_qt(const __bf16* __restrict__ x,
                                            const float* __restrict__ phi_l,
                                            __hip_bfloat16* __restrict__ qbf,
                                            __hip_bfloat16* __restrict__ qT) {
    __shared__ __align__(16) __bf16 tile[64][76];
    int t0 = blockIdx.x * 64, e0 = blockIdx.y * 64, b = blockIdx.z;
    int tid = threadIdx.x;
    float ph[8];
#pragma unroll
    for (int j = 0; j < 8; j++) ph[j] = phi_l[j];
#pragma unroll
    for (int k = 0; k < 2; k++) {
        int idx = k * 256 + tid;
        int r = idx >> 3, hh = idx & 7;           // row, head-slot (8 e each)
        bf16x8 xv = *(const bf16x8*)(x + ((size_t)b * S_ + t0 + r) * E_ + e0 + hh * 8);
        float c[8];
#pragma unroll
        for (int j = 0; j < 8; j++) c[j] = __cosf((float)xv[j] + ph[j]);
        float q[8];
        float run = c[0];
#pragma unroll
        for (int i = 1; i < 8; i++) { run *= c[i]; q[i] = run; }
        float o0 = c[1];
#pragma unroll
        for (int i = 2; i < 8; i++) o0 *= c[i];
        q[0] = o0;
        bf16x8 v;
#pragma unroll
        for (int j = 0; j < 8; j++) v[j] = (__bf16)q[j];
        *(bf16x8*)(qbf + ((size_t)b * S_ + t0 + r) * E_ + e0 + hh * 8) = v;
        *(bf16x8*)&tile[r][hh * 8] = v;
    }
    __syncthreads();
#pragma unroll
    for (int k = 0; k < 2; k++) {
        int idx = k * 256 + tid;
        int el = idx >> 3, tc = idx & 7;          // e-local, t-chunk
        bf16x8 v;
#pragma unroll
        for (int j = 0; j < 8; j++) v[j] = tile[tc * 8 + j][el];
        *(bf16x8*)(qT + ((size_t)b * E_ + e0 + el) * S_ + t0 + tc * 8) = v;
    }
}

// ---------------- flash attention: Wq=32, KVBLK=32, K+V via global_load_lds, vtile dbuf ----------------
// p = exp(s - 44): |s| <= 90.5, diag s_ii >= 0 => no overflow, row-sum >= e^-44.
// Mathematically identical to softmax. 1D grid 512: b = bid&7 (batch->XCD pin).
// R20/R22-measured best (58us): shared-P 32qx128e, 2 barriers/iter. FROZEN.
__global__ __launch_bounds__(256, 2) void k_attn(const __hip_bfloat16* __restrict__ qbf,
                                                 const __hip_bfloat16* __restrict__ qT,
                                                 __bf16* __restrict__ pacc,
                                                 float* __restrict__ pl) {
    __shared__ __align__(16) __bf16 ktile[KVBLK * 256];     // 16KB [kv32][e256], chunk ^= r&7
    __shared__ __align__(16) __bf16 vtile[2][256 * KVBLK];  // 2x16KB [e][kv32], chunk ^= (e>>1)&3
    __shared__ __align__(16) __bf16 plds[2][32][36];        // 4.6KB [rg][q32][kv32+4] (18-word rows)
    __shared__ float redl[2][32][2];
    const float SCALE = 0.3535533905932738f;                // 1/sqrt(8)
    int bid  = blockIdx.x;
    int b    = bid & 7;                                     // batch == XCD
    int qt   = (bid >> 3) & 31;
    int z    = bid >> 8;
    int tid  = threadIdx.x;
    int wv   = tid >> 6;
    int lane = tid & 63;
    int r16  = lane & 15;
    int kg   = lane >> 4;
    int rg   = wv >> 1, eh = wv & 1;
    int qrow0 = qt * 64 + rg * 32;
    int ebase = eh * 128;

    bf16x8 aq[2][8];
#pragma unroll
    for (int qs = 0; qs < 2; qs++)
#pragma unroll
        for (int kk = 0; kk < 8; kk++)
            aq[qs][kk] = *(const bf16x8*)(qbf + ((size_t)b * S_ + qrow0 + qs * 16 + r16) * E_ + kk * 32 + kg * 8);

    f32x4 acc0[8], acc1[8];
#pragma unroll
    for (int cf = 0; cf < 8; cf++) { acc0[cf] = (f32x4){0.f,0.f,0.f,0.f}; acc1[cf] = (f32x4){0.f,0.f,0.f,0.f}; }
    float lrow0[4] = {0.f,0.f,0.f,0.f}, lrow1[4] = {0.f,0.f,0.f,0.f};

    constexpr int SPAN = S_ / NSPLIT;
    constexpr int NT = SPAN / KVBLK;    // 32
    int k0 = z * SPAN;

    auto issue_k = [&](int kb) {
#pragma unroll
        for (int c = 0; c < 4; c++) {
            int seg = wv * 4 + c;                       // 16 x 1KB segments (32 rows x 512B)
            int r = seg * 2 + (lane >> 5);
            int ch = lane & 31;
            const __hip_bfloat16* src = qbf + ((size_t)b * S_ + kb + r) * E_ + ((ch ^ (r & 7)) * 8);
            __builtin_amdgcn_global_load_lds((const __attribute__((address_space(1))) void*)src,
                                             (__attribute__((address_space(3))) void*)(ktile + seg * 512),
                                             16, 0, 0);
        }
    };
    auto issue_v = [&](int kb, int buf) {
#pragma unroll
        for (int c = 0; c < 4; c++) {
            int seg = wv * 4 + c;                       // 16 x 1KB segments (16 e-rows x 64B each)
            int e = seg * 16 + (lane >> 2);
            int ch = lane & 3;
            const __hip_bfloat16* src = qT + ((size_t)b * E_ + e) * S_ + kb + ((ch ^ ((e >> 1) & 3)) * 8);
            __builtin_amdgcn_global_load_lds((const __attribute__((address_space(1))) void*)src,
                                             (__attribute__((address_space(3))) void*)(&vtile[buf][seg * 512]),
                                             16, 0, 0);
        }
    };

    // prologue: tile 0
    issue_k(k0);
    issue_v(k0, 0);
    asm volatile("s_waitcnt vmcnt(0)" ::: "memory");
    __syncthreads();

    for (int kt = 0; kt < NT; kt++) {
        int vcur = kt & 1;
        // ---- QK^T: this wave's kv-half [eh*16, eh*16+16) ----
        f32x4 s0 = (f32x4){0.f,0.f,0.f,0.f}, s1 = (f32x4){0.f,0.f,0.f,0.f};
#pragma unroll
        for (int kk = 0; kk < 8; kk++) {
            bf16x8 bk = *(const bf16x8*)&ktile[(eh * 16 + r16) * 256 + (((kk * 4 + kg) ^ (r16 & 7)) * 8)];
            s0 = MFMA16(aq[0][kk], bk, s0);
            s1 = MFMA16(aq[1][kk], bk, s1);
        }
#pragma unroll
        for (int i = 0; i < 4; i++) {
            float p0 = __expf(fmaf(s0[i], SCALE, -44.0f));
            float p1 = __expf(fmaf(s1[i], SCALE, -44.0f));
            plds[rg][kg * 4 + i][eh * 16 + r16]      = (__bf16)p0;
            plds[rg][16 + kg * 4 + i][eh * 16 + r16] = (__bf16)p1;
            lrow0[i] += p0;
            lrow1[i] += p1;
        }
        __syncthreads();                         // B2: P complete; ktile/vtile[vcur^1] reads done
        bool more = (kt + 1 < NT);
        if (more) {                              // async into ktile + vtile[vcur^1]; lands under PV
            int kn = k0 + (kt + 1) * KVBLK;
            issue_k(kn);
            issue_v(kn, vcur ^ 1);
        }
        // ---- PV ----
        bf16x8 pa0 = *(const bf16x8*)&plds[rg][r16][kg * 8];
        bf16x8 pa1 = *(const bf16x8*)&plds[rg][16 + r16][kg * 8];
#pragma unroll
        for (int cf = 0; cf < 8; cf++) {
            int vrow = ebase + cf * 16 + r16;
            bf16x8 bv = *(const bf16x8*)&vtile[vcur][vrow * KVBLK + ((kg ^ ((vrow >> 1) & 3)) * 8)];
            acc0[cf] = MFMA16(pa0, bv, acc0[cf]);
            acc1[cf] = MFMA16(pa1, bv, acc1[cf]);
        }
        if (more) {
            asm volatile("s_waitcnt vmcnt(0)" ::: "memory");
            __syncthreads();                     // B1: all waves' loads landed
        }
    }

    // ---- epilogue: l totals then partial writes (bf16) ----
#pragma unroll
    for (int i = 0; i < 4; i++) {
#pragma unroll
        for (int m = 1; m <= 8; m <<= 1) {
            lrow0[i] += __shfl_xor(lrow0[i], m);
            lrow1[i] += __shfl_xor(lrow1[i], m);
        }
    }
    if (r16 == 0) {
#pragma unroll
        for (int i = 0; i < 4; i++) {
            redl[rg][kg * 4 + i][eh]      = lrow0[i];
            redl[rg][16 + kg * 4 + i][eh] = lrow1[i];
        }
    }
    __syncthreads();
    size_t prow0 = (size_t)z * BS_ + (size_t)b * S_ + qrow0;
    if (eh == 0 && r16 == 0) {
#pragma unroll
        for (int i = 0; i < 4; i++) {
            int q = kg * 4 + i;
            pl[prow0 + q]      = redl[rg][q][0] + redl[rg][q][1];
            pl[prow0 + 16 + q] = redl[rg][16 + q][0] + redl[rg][16 + q][1];
        }
    }
#pragma unroll
    for (int i = 0; i < 4; i++) {
#pragma unroll
        for (int cf = 0; cf < 8; cf++) {
            pacc[(prow0 + kg * 4 + i) * E_ + ebase + cf * 16 + r16]      = (__bf16)acc0[cf][i];
            pacc[(prow0 + 16 + kg * 4 + i) * E_ + ebase + cf * 16 + r16] = (__bf16)acc1[cf][i];
        }
    }
}

// ---------------- fused merge (2 bf16 partials) + residual + layernorm (bf16 x) ----------------
__global__ __launch_bounds__(256) void k_aln(const __bf16* __restrict__ pacc,
                                             const float* __restrict__ pl,
                                             __bf16* __restrict__ x,
                                             const float* __restrict__ g,
                                             const float* __restrict__ bb) {
    int wv = threadIdx.x >> 6, lane = threadIdx.x & 63;
    size_t row = (size_t)blockIdx.x * 4 + wv;
    float inv = 1.0f / (pl[row] + pl[BS_ + row]);
    bf16x4 a0 = ((const bf16x4*)(pacc + row * E_))[lane];
    bf16x4 a1 = ((const bf16x4*)(pacc + (size_t)BS_ * E_ + row * E_))[lane];
    bf16x4 xv = ((const bf16x4*)(x + row * E_))[lane];
    f32x4 v;
    float s = 0.f, sq = 0.f;
#pragma unroll
    for (int j = 0; j < 4; j++) {
        v[j] = (float)xv[j] + ((float)a0[j] + (float)a1[j]) * inv;
        s += v[j]; sq += v[j] * v[j];
    }
#pragma unroll
    for (int m = 1; m <= 32; m <<= 1) { s += __shfl_xor(s, m); sq += __shfl_xor(sq, m); }
    float mean = s * (1.f / E_);
    float var = sq * (1.f / E_) - mean * mean;
    float rstd = rsqrtf(var + 1e-5f);
    f32x4 gv = ((const f32x4*)g)[lane];
    f32x4 bv = ((const f32x4*)bb)[lane];
    bf16x4 o;
#pragma unroll
    for (int j = 0; j < 4; j++) o[j] = (__bf16)((v[j] - mean) * rstd * gv[j] + bv[j]);
    ((bf16x4*)(x + row * E_))[lane] = o;
}

// ---------------- W2 transpose to bf16 (tiled): (1024,256) -> (256,1024) ----------------
__global__ __launch_bounds__(256) void k_w2t(const float* __restrict__ W2l,
                                             __hip_bfloat16* __restrict__ w2t) {
    __shared__ __align__(16) __bf16 tile[64][72];
    int k0 = blockIdx.x * 64, e0 = blockIdx.y * 64;
    int tid = threadIdx.x;
#pragma unroll
    for (int half = 0; half < 2; half++) {
        int r  = half * 32 + (tid >> 3);      // k row
        int c8 = (tid & 7) * 8;               // e offset
        f32x4 v0 = *(const f32x4*)(W2l + (size_t)(k0 + r) * E_ + e0 + c8);
        f32x4 v1 = *(const f32x4*)(W2l + (size_t)(k0 + r) * E_ + e0 + c8 + 4);
#pragma unroll
        for (int j = 0; j < 4; j++) { tile[r][c8 + j] = (__bf16)v0[j]; tile[r][c8 + 4 + j] = (__bf16)v1[j]; }
    }
    __syncthreads();
#pragma unroll
    for (int half = 0; half < 2; half++) {
        int e  = half * 32 + (tid >> 3);
        int k8 = (tid & 7) * 8;
        bf16x8 v;
#pragma unroll
        for (int j = 0; j < 8; j++) v[j] = tile[k8 + j][e];
        *(bf16x8*)(w2t + (size_t)(e0 + e) * FF_ + k0 + k8) = v;
    }
}

// ---------------- fused FFN: rank-8 h + GEMM + bias + residual + LN (bf16 x) ----------------
__global__ __launch_bounds__(256) void k_ffn(__bf16* __restrict__ x,
                                             const float* __restrict__ theta_l,
                                             const float* __restrict__ W1l,
                                             const float* __restrict__ b1l,
                                             const __hip_bfloat16* __restrict__ w2t,
                                             const float* __restrict__ b2l,
                                             const float* __restrict__ g,
                                             const float* __restrict__ bb) {
    __shared__ __align__(16) __bf16 Bld[2][256 * 64];   // [buf][e][k64] linear (global_load_lds dest)
    __shared__ __align__(16) __bf16 Ald[2][32 * 64];    // [buf][r][k64], chunk ^= r&7
    __shared__ float qmld[32][9];
    __shared__ float reds[32][4][2];
    int tid = threadIdx.x;
    int wv = tid >> 6, lane = tid & 63;
    int r16 = lane & 15, kg = lane >> 4;
    int rbase = blockIdx.x * 32;
    int ebQ = wv * 64;
    const int NT = FF_ / 64;   // 16

    {   // qm[r][i] = cos(x[row][i]) * cos(theta[i])
        int r = tid >> 3, i = tid & 7;
        qmld[r][i] = __cosf((float)x[(size_t)(rbase + r) * E_ + i]) * __cosf(theta_l[i]);
    }

    f32x4 w[18];   // W1 chunk (16) + b1 chunk (2), all constant-indexed

    auto issue_B = [&](int kt, int buf) {
#pragma unroll
        for (int s = 0; s < 8; s++) {
            int seg = wv * 8 + s;                       // 32 x 1KB segments
            int e = seg * 8 + (lane >> 3);
            int c = lane & 7;
            const __hip_bfloat16* src = w2t + (size_t)e * FF_ + kt * 64 + ((c ^ (e & 7)) * 8);
            __builtin_amdgcn_global_load_lds((const __attribute__((address_space(1))) void*)src,
                                             (__attribute__((address_space(3))) void*)(&Bld[buf][seg * 512]),
                                             16, 0, 0);
        }
    };
    auto load_W1 = [&](int kt) {
        int c = tid & 7;
        int k = kt * 64 + c * 8;
#pragma unroll
        for (int i = 0; i < 8; i++) {
            w[2 * i]     = *(const f32x4*)(W1l + (size_t)i * FF_ + k);
            w[2 * i + 1] = *(const f32x4*)(W1l + (size_t)i * FF_ + k + 4);
        }
        w[16] = *(const f32x4*)(b1l + k);
        w[17] = *(const f32x4*)(b1l + k + 4);
    };
    auto math_h = [&](int buf) {
        int r = tid >> 3, c = tid & 7;
        f32x4 h0 = w[16], h1 = w[17];
#pragma unroll
        for (int i = 0; i < 8; i++) {
            float qv = qmld[r][i];
#pragma unroll
            for (int j = 0; j < 4; j++) {
                h0[j] = fmaf(qv, w[2 * i][j], h0[j]);
                h1[j] = fmaf(qv, w[2 * i + 1][j], h1[j]);
            }
        }
        bf16x8 hv;
#pragma unroll
        for (int j = 0; j < 4; j++) {
            hv[j]     = (__bf16)fmaxf(h0[j], 0.f);
            hv[4 + j] = (__bf16)fmaxf(h1[j], 0.f);
        }
        *(bf16x8*)&Ald[buf][r * 64 + ((c ^ (r & 7)) * 8)] = hv;
    };

    // prologue
    issue_B(0, 0);
    load_W1(0);
    __syncthreads();          // qmld visible; B(0) drained
    math_h(0);
    __syncthreads();          // Ald[0] visible

    f32x4 acc[2][4];
#pragma unroll
    for (int qs = 0; qs < 2; qs++)
#pragma unroll
        for (int cf = 0; cf < 4; cf++) acc[qs][cf] = (f32x4){0.f, 0.f, 0.f, 0.f};

    for (int kt = 0; kt < NT; kt++) {
        int cur = kt & 1;
        bool more = (kt + 1 < NT);
        if (more) {
            issue_B(kt + 1, cur ^ 1);   // in flight across MFMA phase
            load_W1(kt + 1);            // reg prefetch, consumed after MFMA
        }
        bf16x8 aq[2][2];
#pragma unroll
        for (int qs = 0; qs < 2; qs++)
#pragma unroll
            for (int kk = 0; kk < 2; kk++)
                aq[qs][kk] = *(const bf16x8*)&Ald[cur][(qs * 16 + r16) * 64 + (((kk * 4 + kg) ^ (r16 & 7)) * 8)];
#pragma unroll
        for (int cf = 0; cf < 4; cf++) {
            int e = ebQ + cf * 16 + r16;
#pragma unroll
            for (int kk = 0; kk < 2; kk++) {
                bf16x8 bv = *(const bf16x8*)&Bld[cur][e * 64 + (((kk * 4 + kg) ^ (e & 7)) * 8)];
                acc[0][cf] = MFMA16(aq[0][kk], bv, acc[0][cf]);
                acc[1][cf] = MFMA16(aq[1][kk], bv, acc[1][cf]);
            }
        }
        if (more) {
            math_h(cur ^ 1);            // W1 regs already resident
            __syncthreads();            // drains B(kt+1) + Ald writes; guards buf reuse
        }
    }

    // epilogue: bias + residual + layernorm
    float sA[2][4] = {{0.f,0.f,0.f,0.f},{0.f,0.f,0.f,0.f}};
    float sQ[2][4] = {{0.f,0.f,0.f,0.f},{0.f,0.f,0.f,0.f}};
#pragma unroll
    for (int qs = 0; qs < 2; qs++)
#pragma unroll
        for (int cf = 0; cf < 4; cf++) {
            int e = ebQ + cf * 16 + r16;
            float b2v = b2l[e];
#pragma unroll
            for (int i = 0; i < 4; i++) {
                size_t orow = (size_t)rbase + qs * 16 + kg * 4 + i;
                float t = acc[qs][cf][i] + b2v + (float)x[orow * E_ + e];
                acc[qs][cf][i] = t;
                sA[qs][i] += t; sQ[qs][i] += t * t;
            }
        }
#pragma unroll
    for (int qs = 0; qs < 2; qs++)
#pragma unroll
        for (int i = 0; i < 4; i++) {
#pragma unroll
            for (int m = 1; m <= 8; m <<= 1) {
                sA[qs][i] += __shfl_xor(sA[qs][i], m);
                sQ[qs][i] += __shfl_xor(sQ[qs][i], m);
            }
        }
    if (r16 == 0) {
#pragma unroll
        for (int qs = 0; qs < 2; qs++)
#pragma unroll
            for (int i = 0; i < 4; i++) {
                int row = qs * 16 + kg * 4 + i;
                reds[row][wv][0] = sA[qs][i];
                reds[row][wv][1] = sQ[qs][i];
            }
    }
    __syncthreads();
    float mean[2][4], rstd[2][4];
#pragma unroll
    for (int qs = 0; qs < 2; qs++)
#pragma unroll
        for (int i = 0; i < 4; i++) {
            int row = qs * 16 + kg * 4 + i;
            float S = reds[row][0][0] + reds[row][1][0] + reds[row][2][0] + reds[row][3][0];
            float Q = reds[row][0][1] + reds[row][1][1] + reds[row][2][1] + reds[row][3][1];
            mean[qs][i] = S * (1.f / E_);
            float var = Q * (1.f / E_) - mean[qs][i] * mean[qs][i];
            rstd[qs][i] = rsqrtf(var + 1e-5f);
        }
#pragma unroll
    for (int qs = 0; qs < 2; qs++)
#pragma unroll
        for (int cf = 0; cf < 4; cf++) {
            int e = ebQ + cf * 16 + r16;
            float gv = g[e], bv = bb[e];
#pragma unroll
            for (int i = 0; i < 4; i++) {
                size_t orow = (size_t)rbase + qs * 16 + kg * 4 + i;
                x[orow * E_ + e] = (__bf16)((acc[qs][cf][i] - mean[qs][i]) * rstd[qs][i] * gv + bv);
            }
        }
}

// ---------------- mean over S (two-stage, deterministic; bf16 x) ----------------
__global__ __launch_bounds__(256) void k_mean(const __bf16* __restrict__ x, float* __restrict__ psum) {
    int c = blockIdx.x, b = blockIdx.y, e = threadIdx.x;
    float s = 0.f;
    size_t base = ((size_t)b * S_ + c * 128) * E_ + e;
    for (int r = 0; r < 128; r++) s += (float)x[base + (size_t)r * E_];
    psum[(c * 8 + b) * E_ + e] = s;
}

__global__ __launch_bounds__(256) void k_mean2(const float* __restrict__ psum, float* __restrict__ xmean) {
    int idx = blockIdx.x * 256 + threadIdx.x;   // 0..2047 -> (b,e)
    int b = idx >> 8, e = idx & 255;
    float s = 0.f;
    for (int c = 0; c < 16; c++) s += psum[(c * 8 + b) * E_ + e];
    xmean[idx] = s * (1.f / S_);
}

// ---------------- classifier ----------------
__global__ __launch_bounds__(128) void k_cls(const float* __restrict__ xmean,
                                             const float* __restrict__ Wc,
                                             const float* __restrict__ bc,
                                             float* __restrict__ outp) {
    int t = threadIdx.x;
    if (t >= B_ * NC_) return;
    int b = t / NC_, c = t % NC_;
    float s = bc[c];
    for (int e = 0; e < E_; e++) s += xmean[b * E_ + e] * Wc[e * NC_ + c];
    outp[t] = s;
}

extern "C" void kernel_launch(void* const* d_in, const int* in_sizes, int n_in,
                              void* d_out, int out_size, void* d_ws, size_t ws_size,
                              hipStream_t stream) {
    (void)in_sizes; (void)n_in; (void)out_size; (void)ws_size;
    const int*   tokens = (const int*)d_in[0];
    const float* emb    = (const float*)d_in[1];
    const float* phi    = (const float*)d_in[2];
    const float* theta  = (const float*)d_in[3];
    const float* W1     = (const float*)d_in[4];
    const float* b1     = (const float*)d_in[5];
    const float* W2     = (const float*)d_in[6];
    const float* b2     = (const float*)d_in[7];
    const float* g1     = (const float*)d_in[8];
    const float* beta1  = (const float*)d_in[9];
    const float* g2     = (const float*)d_in[10];
    const float* beta2  = (const float*)d_in[11];
    const float* Wc     = (const float*)d_in[12];
    const float* bc     = (const float*)d_in[13];
    float* outp = (float*)d_out;

    // workspace layout (bf16 residual stream; NSPLIT=2; w2t holds all 4 layers; pacc bf16)
    __bf16* xbuf = (__bf16*)d_ws;                                      // BS_*E_ bf16
    __hip_bfloat16* qbf = (__hip_bfloat16*)(xbuf + (size_t)BS_ * E_);  // BS_*E_ bf16
    __hip_bfloat16* qT  = qbf + (size_t)BS_ * E_;                      // BS_*E_ bf16
    __hip_bfloat16* w2t = qT + (size_t)BS_ * E_;                       // 4*E_*FF_ bf16
    float* psum  = (float*)(w2t + (size_t)4 * E_ * FF_);               // 16*8*E_ f32
    float* xmean = psum + 16 * 8 * E_;                                 // B_*E_ f32
    float* pl    = xmean + B_ * E_;                                    // NSPLIT*BS_ f32
    __bf16* pacc = (__bf16*)(pl + (size_t)NSPLIT * BS_);               // NSPLIT*BS_*E_ bf16

    k_embed<<<BS_, 256, 0, stream>>>(tokens, emb, xbuf);
    for (int l = 0; l < 4; l++)      // layer-static: hoisted out of the layer loop
        k_w2t<<<dim3(FF_ / 64, E_ / 64), 256, 0, stream>>>(W2 + (size_t)l * FF_ * E_,
                                                           w2t + (size_t)l * E_ * FF_);

    for (int l = 0; l < 4; l++) {
        k_qt<<<dim3(S_ / 64, E_ / 64, B_), 256, 0, stream>>>(xbuf, phi + l * NQ_, qbf, qT);
        k_attn<<<(S_ / 64) * B_ * NSPLIT, 256, 0, stream>>>(qbf, qT, pacc, pl);
        k_aln<<<BS_ / 4, 256, 0, stream>>>(pacc, pl, xbuf, g1 + l * E_, beta1 + l * E_);
        k_ffn<<<BS_ / 32, 256, 0, stream>>>(xbuf, theta + l * NQ_,
                                            W1 + (size_t)l * NQ_ * FF_, b1 + (size_t)l * FF_,
                                            w2t + (size_t)l * E_ * FF_, b2 + (size_t)l * E_,
                                            g2 + l * E_, beta2 + l * E_);
    }

    k_mean<<<dim3(16, B_), 256, 0, stream>>>(xbuf, psum);
    k_mean2<<<8, 256, 0, stream>>>(psum, xmean);
    k_cls<<<1, 128, 0, stream>>>(xmean, Wc, bc, outp);
}

// Round 24
// 420.906 us; speedup vs baseline: 1.0816x; 1.0113x over previous
//
#include <hip/hip_runtime.h>
#include <hip/hip_bf16.h>

#define B_ 8
#define S_ 2048
#define E_ 256
#define FF_ 1024
#define NQ_ 8
#define NC_ 10
#define BS_ (B_*S_)
#define NSPLIT 2
#define KVBLK 32

typedef __bf16 bf16x8 __attribute__((ext_vector_type(8)));
typedef __bf16 bf16x4 __attribute__((ext_vector_type(4)));
typedef float f32x4 __attribute__((ext_vector_type(4)));

#define MFMA16(a,b,c) __builtin_amdgcn_mfma_f32_16x16x32_bf16(a,b,c,0,0,0)

// ---------------- embed + positional encoding (bf16 residual stream) ----------------
__global__ __launch_bounds__(256) void k_embed(const int* __restrict__ tokens,
                                               const float* __restrict__ emb,
                                               __bf16* __restrict__ x) {
    int row = blockIdx.x;           // 0..BS_-1
    int e = threadIdx.x;            // 0..255
    int s = row & (S_ - 1);
    int tok = tokens[row];
    int i2 = e & ~1;                // 2*(e/2)
    float d = __expf((float)i2 * (-9.210340371976184f / 256.0f));
    float ang = (float)s * d;
    float pe = (e & 1) ? __cosf(ang) : __sinf(ang);
    x[(size_t)row * E_ + e] = (__bf16)(emb[(size_t)tok * E_ + e] + pe);
}

// ---------------- fused q-compute + transpose (layer 0 only; reads bf16 x) ----------------
__global__ __launch_bounds__(256) void k_qt(const __bf16* __restrict__ x,
                                            const float* __restrict__ phi_l,
                                            __hip_bfloat16* __restrict__ qbf,
                                            __hip_bfloat16* __restrict__ qT) {
    __shared__ __align__(16) __bf16 tile[64][76];
    int t0 = blockIdx.x * 64, e0 = blockIdx.y * 64, b = blockIdx.z;
    int tid = threadIdx.x;
    float ph[8];
#pragma unroll
    for (int j = 0; j < 8; j++) ph[j] = phi_l[j];
#pragma unroll
    for (int k = 0; k < 2; k++) {
        int idx = k * 256 + tid;
        int r = idx >> 3, hh = idx & 7;           // row, head-slot (8 e each)
        bf16x8 xv = *(const bf16x8*)(x + ((size_t)b * S_ + t0 + r) * E_ + e0 + hh * 8);
        float c[8];
#pragma unroll
        for (int j = 0; j < 8; j++) c[j] = __cosf((float)xv[j] + ph[j]);
        float q[8];
        float run = c[0];
#pragma unroll
        for (int i = 1; i < 8; i++) { run *= c[i]; q[i] = run; }
        float o0 = c[1];
#pragma unroll
        for (int i = 2; i < 8; i++) o0 *= c[i];
        q[0] = o0;
        bf16x8 v;
#pragma unroll
        for (int j = 0; j < 8; j++) v[j] = (__bf16)q[j];
        *(bf16x8*)(qbf + ((size_t)b * S_ + t0 + r) * E_ + e0 + hh * 8) = v;
        *(bf16x8*)&tile[r][hh * 8] = v;
    }
    __syncthreads();
#pragma unroll
    for (int k = 0; k < 2; k++) {
        int idx = k * 256 + tid;
        int el = idx >> 3, tc = idx & 7;          // e-local, t-chunk
        bf16x8 v;
#pragma unroll
        for (int j = 0; j < 8; j++) v[j] = tile[tc * 8 + j][el];
        *(bf16x8*)(qT + ((size_t)b * E_ + e0 + el) * S_ + t0 + tc * 8) = v;
    }
}

// ---------------- flash attention: Wq=32, KVBLK=32, K+V via global_load_lds, vtile dbuf ----------------
// p = exp(s - 44): |s| <= 90.5, diag s_ii >= 0 => no overflow, row-sum >= e^-44.
// Mathematically identical to softmax. 1D grid 512: b = bid&7 (batch->XCD pin).
// R20/R22-measured best (58us): shared-P 32qx128e, 2 barriers/iter. FROZEN.
__global__ __launch_bounds__(256, 2) void k_attn(const __hip_bfloat16* __restrict__ qbf,
                                                 const __hip_bfloat16* __restrict__ qT,
                                                 __bf16* __restrict__ pacc,
                                                 float* __restrict__ pl) {
    __shared__ __align__(16) __bf16 ktile[KVBLK * 256];     // 16KB [kv32][e256], chunk ^= r&7
    __shared__ __align__(16) __bf16 vtile[2][256 * KVBLK];  // 2x16KB [e][kv32], chunk ^= (e>>1)&3
    __shared__ __align__(16) __bf16 plds[2][32][36];        // 4.6KB [rg][q32][kv32+4] (18-word rows)
    __shared__ float redl[2][32][2];
    const float SCALE = 0.3535533905932738f;                // 1/sqrt(8)
    int bid  = blockIdx.x;
    int b    = bid & 7;                                     // batch == XCD
    int qt   = (bid >> 3) & 31;
    int z    = bid >> 8;
    int tid  = threadIdx.x;
    int wv   = tid >> 6;
    int lane = tid & 63;
    int r16  = lane & 15;
    int kg   = lane >> 4;
    int rg   = wv >> 1, eh = wv & 1;
    int qrow0 = qt * 64 + rg * 32;
    int ebase = eh * 128;

    bf16x8 aq[2][8];
#pragma unroll
    for (int qs = 0; qs < 2; qs++)
#pragma unroll
        for (int kk = 0; kk < 8; kk++)
            aq[qs][kk] = *(const bf16x8*)(qbf + ((size_t)b * S_ + qrow0 + qs * 16 + r16) * E_ + kk * 32 + kg * 8);

    f32x4 acc0[8], acc1[8];
#pragma unroll
    for (int cf = 0; cf < 8; cf++) { acc0[cf] = (f32x4){0.f,0.f,0.f,0.f}; acc1[cf] = (f32x4){0.f,0.f,0.f,0.f}; }
    float lrow0[4] = {0.f,0.f,0.f,0.f}, lrow1[4] = {0.f,0.f,0.f,0.f};

    constexpr int SPAN = S_ / NSPLIT;
    constexpr int NT = SPAN / KVBLK;    // 32
    int k0 = z * SPAN;

    auto issue_k = [&](int kb) {
#pragma unroll
        for (int c = 0; c < 4; c++) {
            int seg = wv * 4 + c;                       // 16 x 1KB segments (32 rows x 512B)
            int r = seg * 2 + (lane >> 5);
            int ch = lane & 31;
            const __hip_bfloat16* src = qbf + ((size_t)b * S_ + kb + r) * E_ + ((ch ^ (r & 7)) * 8);
            __builtin_amdgcn_global_load_lds((const __attribute__((address_space(1))) void*)src,
                                             (__attribute__((address_space(3))) void*)(ktile + seg * 512),
                                             16, 0, 0);
        }
    };
    auto issue_v = [&](int kb, int buf) {
#pragma unroll
        for (int c = 0; c < 4; c++) {
            int seg = wv * 4 + c;                       // 16 x 1KB segments (16 e-rows x 64B each)
            int e = seg * 16 + (lane >> 2);
            int ch = lane & 3;
            const __hip_bfloat16* src = qT + ((size_t)b * E_ + e) * S_ + kb + ((ch ^ ((e >> 1) & 3)) * 8);
            __builtin_amdgcn_global_load_lds((const __attribute__((address_space(1))) void*)src,
                                             (__attribute__((address_space(3))) void*)(&vtile[buf][seg * 512]),
                                             16, 0, 0);
        }
    };

    // prologue: tile 0
    issue_k(k0);
    issue_v(k0, 0);
    asm volatile("s_waitcnt vmcnt(0)" ::: "memory");
    __syncthreads();

    for (int kt = 0; kt < NT; kt++) {
        int vcur = kt & 1;
        // ---- QK^T: this wave's kv-half [eh*16, eh*16+16) ----
        f32x4 s0 = (f32x4){0.f,0.f,0.f,0.f}, s1 = (f32x4){0.f,0.f,0.f,0.f};
#pragma unroll
        for (int kk = 0; kk < 8; kk++) {
            bf16x8 bk = *(const bf16x8*)&ktile[(eh * 16 + r16) * 256 + (((kk * 4 + kg) ^ (r16 & 7)) * 8)];
            s0 = MFMA16(aq[0][kk], bk, s0);
            s1 = MFMA16(aq[1][kk], bk, s1);
        }
#pragma unroll
        for (int i = 0; i < 4; i++) {
            float p0 = __expf(fmaf(s0[i], SCALE, -44.0f));
            float p1 = __expf(fmaf(s1[i], SCALE, -44.0f));
            plds[rg][kg * 4 + i][eh * 16 + r16]      = (__bf16)p0;
            plds[rg][16 + kg * 4 + i][eh * 16 + r16] = (__bf16)p1;
            lrow0[i] += p0;
            lrow1[i] += p1;
        }
        __syncthreads();                         // B2: P complete; ktile/vtile[vcur^1] reads done
        bool more = (kt + 1 < NT);
        if (more) {                              // async into ktile + vtile[vcur^1]; lands under PV
            int kn = k0 + (kt + 1) * KVBLK;
            issue_k(kn);
            issue_v(kn, vcur ^ 1);
        }
        // ---- PV ----
        bf16x8 pa0 = *(const bf16x8*)&plds[rg][r16][kg * 8];
        bf16x8 pa1 = *(const bf16x8*)&plds[rg][16 + r16][kg * 8];
#pragma unroll
        for (int cf = 0; cf < 8; cf++) {
            int vrow = ebase + cf * 16 + r16;
            bf16x8 bv = *(const bf16x8*)&vtile[vcur][vrow * KVBLK + ((kg ^ ((vrow >> 1) & 3)) * 8)];
            acc0[cf] = MFMA16(pa0, bv, acc0[cf]);
            acc1[cf] = MFMA16(pa1, bv, acc1[cf]);
        }
        if (more) {
            asm volatile("s_waitcnt vmcnt(0)" ::: "memory");
            __syncthreads();                     // B1: all waves' loads landed
        }
    }

    // ---- epilogue: l totals then partial writes (bf16) ----
#pragma unroll
    for (int i = 0; i < 4; i++) {
#pragma unroll
        for (int m = 1; m <= 8; m <<= 1) {
            lrow0[i] += __shfl_xor(lrow0[i], m);
            lrow1[i] += __shfl_xor(lrow1[i], m);
        }
    }
    if (r16 == 0) {
#pragma unroll
        for (int i = 0; i < 4; i++) {
            redl[rg][kg * 4 + i][eh]      = lrow0[i];
            redl[rg][16 + kg * 4 + i][eh] = lrow1[i];
        }
    }
    __syncthreads();
    size_t prow0 = (size_t)z * BS_ + (size_t)b * S_ + qrow0;
    if (eh == 0 && r16 == 0) {
#pragma unroll
        for (int i = 0; i < 4; i++) {
            int q = kg * 4 + i;
            pl[prow0 + q]      = redl[rg][q][0] + redl[rg][q][1];
            pl[prow0 + 16 + q] = redl[rg][16 + q][0] + redl[rg][16 + q][1];
        }
    }
#pragma unroll
    for (int i = 0; i < 4; i++) {
#pragma unroll
        for (int cf = 0; cf < 8; cf++) {
            pacc[(prow0 + kg * 4 + i) * E_ + ebase + cf * 16 + r16]      = (__bf16)acc0[cf][i];
            pacc[(prow0 + 16 + kg * 4 + i) * E_ + ebase + cf * 16 + r16] = (__bf16)acc1[cf][i];
        }
    }
}

// ---------------- fused merge (2 bf16 partials) + residual + layernorm (bf16 x) ----------------
__global__ __launch_bounds__(256) void k_aln(const __bf16* __restrict__ pacc,
                                             const float* __restrict__ pl,
                                             __bf16* __restrict__ x,
                                             const float* __restrict__ g,
                                             const float* __restrict__ bb) {
    int wv = threadIdx.x >> 6, lane = threadIdx.x & 63;
    size_t row = (size_t)blockIdx.x * 4 + wv;
    float inv = 1.0f / (pl[row] + pl[BS_ + row]);
    bf16x4 a0 = ((const bf16x4*)(pacc + row * E_))[lane];
    bf16x4 a1 = ((const bf16x4*)(pacc + (size_t)BS_ * E_ + row * E_))[lane];
    bf16x4 xv = ((const bf16x4*)(x + row * E_))[lane];
    f32x4 v;
    float s = 0.f, sq = 0.f;
#pragma unroll
    for (int j = 0; j < 4; j++) {
        v[j] = (float)xv[j] + ((float)a0[j] + (float)a1[j]) * inv;
        s += v[j]; sq += v[j] * v[j];
    }
#pragma unroll
    for (int m = 1; m <= 32; m <<= 1) { s += __shfl_xor(s, m); sq += __shfl_xor(sq, m); }
    float mean = s * (1.f / E_);
    float var = sq * (1.f / E_) - mean * mean;
    float rstd = rsqrtf(var + 1e-5f);
    f32x4 gv = ((const f32x4*)g)[lane];
    f32x4 bv = ((const f32x4*)bb)[lane];
    bf16x4 o;
#pragma unroll
    for (int j = 0; j < 4; j++) o[j] = (__bf16)((v[j] - mean) * rstd * gv[j] + bv[j]);
    ((bf16x4*)(x + row * E_))[lane] = o;
}

// ---------------- W2 transpose to bf16 (tiled): (1024,256) -> (256,1024) ----------------
__global__ __launch_bounds__(256) void k_w2t(const float* __restrict__ W2l,
                                             __hip_bfloat16* __restrict__ w2t) {
    __shared__ __align__(16) __bf16 tile[64][72];
    int k0 = blockIdx.x * 64, e0 = blockIdx.y * 64;
    int tid = threadIdx.x;
#pragma unroll
    for (int half = 0; half < 2; half++) {
        int r  = half * 32 + (tid >> 3);      // k row
        int c8 = (tid & 7) * 8;               // e offset
        f32x4 v0 = *(const f32x4*)(W2l + (size_t)(k0 + r) * E_ + e0 + c8);
        f32x4 v1 = *(const f32x4*)(W2l + (size_t)(k0 + r) * E_ + e0 + c8 + 4);
#pragma unroll
        for (int j = 0; j < 4; j++) { tile[r][c8 + j] = (__bf16)v0[j]; tile[r][c8 + 4 + j] = (__bf16)v1[j]; }
    }
    __syncthreads();
#pragma unroll
    for (int half = 0; half < 2; half++) {
        int e  = half * 32 + (tid >> 3);
        int k8 = (tid & 7) * 8;
        bf16x8 v;
#pragma unroll
        for (int j = 0; j < 8; j++) v[j] = tile[k8 + j][e];
        *(bf16x8*)(w2t + (size_t)(e0 + e) * FF_ + k0 + k8) = v;
    }
}

// ---------------- fused FFN: rank-8 h + GEMM + bias + residual + LN + q-gen for next layer ----------------
// gen_q: epilogue computes q_{l+1} = cumprod(cos(x1 + phi_{l+1})) per 8-lane head group
// (Hillis-Steele product scan; second scan with c0:=1 gives q[0] without division) and
// writes qbf/qT directly — eliminates the separate k_qt pass for layers 1..3.
__global__ __launch_bounds__(256) void k_ffn(__bf16* __restrict__ x,
                                             const float* __restrict__ theta_l,
                                             const float* __restrict__ W1l,
                                             const float* __restrict__ b1l,
                                             const __hip_bfloat16* __restrict__ w2t,
                                             const float* __restrict__ b2l,
                                             const float* __restrict__ g,
                                             const float* __restrict__ bb,
                                             const float* __restrict__ phi_next,
                                             __bf16* __restrict__ qbf,
                                             __bf16* __restrict__ qT,
                                             int gen_q) {
    __shared__ __align__(16) __bf16 Bld[2][256 * 64];   // [buf][e][k64] linear (global_load_lds dest)
    __shared__ __align__(16) __bf16 Ald[2][32 * 64];    // [buf][r][k64], chunk ^= r&7
    __shared__ float qmld[32][9];
    __shared__ float reds[32][4][2];
    int tid = threadIdx.x;
    int wv = tid >> 6, lane = tid & 63;
    int r16 = lane & 15, kg = lane >> 4;
    int rbase = blockIdx.x * 32;
    int ebQ = wv * 64;
    const int NT = FF_ / 64;   // 16

    {   // qm[r][i] = cos(x[row][i]) * cos(theta[i])
        int r = tid >> 3, i = tid & 7;
        qmld[r][i] = __cosf((float)x[(size_t)(rbase + r) * E_ + i]) * __cosf(theta_l[i]);
    }

    f32x4 w[18];   // W1 chunk (16) + b1 chunk (2), all constant-indexed

    auto issue_B = [&](int kt, int buf) {
#pragma unroll
        for (int s = 0; s < 8; s++) {
            int seg = wv * 8 + s;                       // 32 x 1KB segments
            int e = seg * 8 + (lane >> 3);
            int c = lane & 7;
            const __hip_bfloat16* src = w2t + (size_t)e * FF_ + kt * 64 + ((c ^ (e & 7)) * 8);
            __builtin_amdgcn_global_load_lds((const __attribute__((address_space(1))) void*)src,
                                             (__attribute__((address_space(3))) void*)(&Bld[buf][seg * 512]),
                                             16, 0, 0);
        }
    };
    auto load_W1 = [&](int kt) {
        int c = tid & 7;
        int k = kt * 64 + c * 8;
#pragma unroll
        for (int i = 0; i < 8; i++) {
            w[2 * i]     = *(const f32x4*)(W1l + (size_t)i * FF_ + k);
            w[2 * i + 1] = *(const f32x4*)(W1l + (size_t)i * FF_ + k + 4);
        }
        w[16] = *(const f32x4*)(b1l + k);
        w[17] = *(const f32x4*)(b1l + k + 4);
    };
    auto math_h = [&](int buf) {
        int r = tid >> 3, c = tid & 7;
        f32x4 h0 = w[16], h1 = w[17];
#pragma unroll
        for (int i = 0; i < 8; i++) {
            float qv = qmld[r][i];
#pragma unroll
            for (int j = 0; j < 4; j++) {
                h0[j] = fmaf(qv, w[2 * i][j], h0[j]);
                h1[j] = fmaf(qv, w[2 * i + 1][j], h1[j]);
            }
        }
        bf16x8 hv;
#pragma unroll
        for (int j = 0; j < 4; j++) {
            hv[j]     = (__bf16)fmaxf(h0[j], 0.f);
            hv[4 + j] = (__bf16)fmaxf(h1[j], 0.f);
        }
        *(bf16x8*)&Ald[buf][r * 64 + ((c ^ (r & 7)) * 8)] = hv;
    };

    // prologue
    issue_B(0, 0);
    load_W1(0);
    __syncthreads();          // qmld visible; B(0) drained
    math_h(0);
    __syncthreads();          // Ald[0] visible

    f32x4 acc[2][4];
#pragma unroll
    for (int qs = 0; qs < 2; qs++)
#pragma unroll
        for (int cf = 0; cf < 4; cf++) acc[qs][cf] = (f32x4){0.f, 0.f, 0.f, 0.f};

    for (int kt = 0; kt < NT; kt++) {
        int cur = kt & 1;
        bool more = (kt + 1 < NT);
        if (more) {
            issue_B(kt + 1, cur ^ 1);   // in flight across MFMA phase
            load_W1(kt + 1);            // reg prefetch, consumed after MFMA
        }
        bf16x8 aq[2][2];
#pragma unroll
        for (int qs = 0; qs < 2; qs++)
#pragma unroll
            for (int kk = 0; kk < 2; kk++)
                aq[qs][kk] = *(const bf16x8*)&Ald[cur][(qs * 16 + r16) * 64 + (((kk * 4 + kg) ^ (r16 & 7)) * 8)];
#pragma unroll
        for (int cf = 0; cf < 4; cf++) {
            int e = ebQ + cf * 16 + r16;
#pragma unroll
            for (int kk = 0; kk < 2; kk++) {
                bf16x8 bv = *(const bf16x8*)&Bld[cur][e * 64 + (((kk * 4 + kg) ^ (e & 7)) * 8)];
                acc[0][cf] = MFMA16(aq[0][kk], bv, acc[0][cf]);
                acc[1][cf] = MFMA16(aq[1][kk], bv, acc[1][cf]);
            }
        }
        if (more) {
            math_h(cur ^ 1);            // W1 regs already resident
            __syncthreads();            // drains B(kt+1) + Ald writes; guards buf reuse
        }
    }

    // epilogue: bias + residual + layernorm
    float sA[2][4] = {{0.f,0.f,0.f,0.f},{0.f,0.f,0.f,0.f}};
    float sQ[2][4] = {{0.f,0.f,0.f,0.f},{0.f,0.f,0.f,0.f}};
#pragma unroll
    for (int qs = 0; qs < 2; qs++)
#pragma unroll
        for (int cf = 0; cf < 4; cf++) {
            int e = ebQ + cf * 16 + r16;
            float b2v = b2l[e];
#pragma unroll
            for (int i = 0; i < 4; i++) {
                size_t orow = (size_t)rbase + qs * 16 + kg * 4 + i;
                float t = acc[qs][cf][i] + b2v + (float)x[orow * E_ + e];
                acc[qs][cf][i] = t;
                sA[qs][i] += t; sQ[qs][i] += t * t;
            }
        }
#pragma unroll
    for (int qs = 0; qs < 2; qs++)
#pragma unroll
        for (int i = 0; i < 4; i++) {
#pragma unroll
            for (int m = 1; m <= 8; m <<= 1) {
                sA[qs][i] += __shfl_xor(sA[qs][i], m);
                sQ[qs][i] += __shfl_xor(sQ[qs][i], m);
            }
        }
    if (r16 == 0) {
#pragma unroll
        for (int qs = 0; qs < 2; qs++)
#pragma unroll
            for (int i = 0; i < 4; i++) {
                int row = qs * 16 + kg * 4 + i;
                reds[row][wv][0] = sA[qs][i];
                reds[row][wv][1] = sQ[qs][i];
            }
    }
    __syncthreads();
    float mean[2][4], rstd[2][4];
#pragma unroll
    for (int qs = 0; qs < 2; qs++)
#pragma unroll
        for (int i = 0; i < 4; i++) {
            int row = qs * 16 + kg * 4 + i;
            float S = reds[row][0][0] + reds[row][1][0] + reds[row][2][0] + reds[row][3][0];
            float Q = reds[row][0][1] + reds[row][1][1] + reds[row][2][1] + reds[row][3][1];
            mean[qs][i] = S * (1.f / E_);
            float var = Q * (1.f / E_) - mean[qs][i] * mean[qs][i];
            rstd[qs][i] = rsqrtf(var + 1e-5f);
        }
    // final x1 (keep in acc for q-gen) + store
#pragma unroll
    for (int qs = 0; qs < 2; qs++)
#pragma unroll
        for (int cf = 0; cf < 4; cf++) {
            int e = ebQ + cf * 16 + r16;
            float gv = g[e], bv = bb[e];
#pragma unroll
            for (int i = 0; i < 4; i++) {
                size_t orow = (size_t)rbase + qs * 16 + kg * 4 + i;
                float xn = (acc[qs][cf][i] - mean[qs][i]) * rstd[qs][i] * gv + bv;
                acc[qs][cf][i] = xn;
                x[orow * E_ + e] = (__bf16)xn;
            }
        }
    // q-gen for next layer: per 8-lane head group product scans (no division)
    if (gen_q) {
        int bq = rbase / S_;
        int trow0 = rbase % S_;
        float ph = phi_next[r16 & 7];
        int hp = r16 & 7;
#pragma unroll
        for (int qs = 0; qs < 2; qs++)
#pragma unroll
            for (int cf = 0; cf < 4; cf++) {
                int e = ebQ + cf * 16 + r16;
#pragma unroll
                for (int i = 0; i < 4; i++) {
                    float c = __cosf(acc[qs][cf][i] + ph);
                    float scan = c;                         // incl prefix prod of c
                    float cp = (hp == 0) ? 1.f : c;         // same with c0 := 1
#pragma unroll
                    for (int d = 1; d <= 4; d <<= 1) {
                        float t1 = __shfl_up(scan, d, 8);
                        float t2 = __shfl_up(cp, d, 8);
                        if (hp >= d) { scan *= t1; cp *= t2; }
                    }
                    float q0 = __shfl(cp, 7, 8);            // prod c1..c7
                    float qv = (hp == 0) ? q0 : scan;
                    int trow = trow0 + qs * 16 + kg * 4 + i;
                    __bf16 qb = (__bf16)qv;
                    qbf[((size_t)bq * S_ + trow) * E_ + e] = qb;
                    qT[((size_t)bq * E_ + e) * S_ + trow]  = qb;
                }
            }
    }
}

// ---------------- mean over S (two-stage, deterministic; bf16 x) ----------------
__global__ __launch_bounds__(256) void k_mean(const __bf16* __restrict__ x, float* __restrict__ psum) {
    int c = blockIdx.x, b = blockIdx.y, e = threadIdx.x;
    float s = 0.f;
    size_t base = ((size_t)b * S_ + c * 128) * E_ + e;
    for (int r = 0; r < 128; r++) s += (float)x[base + (size_t)r * E_];
    psum[(c * 8 + b) * E_ + e] = s;
}

__global__ __launch_bounds__(256) void k_mean2(const float* __restrict__ psum, float* __restrict__ xmean) {
    int idx = blockIdx.x * 256 + threadIdx.x;   // 0..2047 -> (b,e)
    int b = idx >> 8, e = idx & 255;
    float s = 0.f;
    for (int c = 0; c < 16; c++) s += psum[(c * 8 + b) * E_ + e];
    xmean[idx] = s * (1.f / S_);
}

// ---------------- classifier ----------------
__global__ __launch_bounds__(128) void k_cls(const float* __restrict__ xmean,
                                             const float* __restrict__ Wc,
                                             const float* __restrict__ bc,
                                             float* __restrict__ outp) {
    int t = threadIdx.x;
    if (t >= B_ * NC_) return;
    int b = t / NC_, c = t % NC_;
    float s = bc[c];
    for (int e = 0; e < E_; e++) s += xmean[b * E_ + e] * Wc[e * NC_ + c];
    outp[t] = s;
}

extern "C" void kernel_launch(void* const* d_in, const int* in_sizes, int n_in,
                              void* d_out, int out_size, void* d_ws, size_t ws_size,
                              hipStream_t stream) {
    (void)in_sizes; (void)n_in; (void)out_size; (void)ws_size;
    const int*   tokens = (const int*)d_in[0];
    const float* emb    = (const float*)d_in[1];
    const float* phi    = (const float*)d_in[2];
    const float* theta  = (const float*)d_in[3];
    const float* W1     = (const float*)d_in[4];
    const float* b1     = (const float*)d_in[5];
    const float* W2     = (const float*)d_in[6];
    const float* b2     = (const float*)d_in[7];
    const float* g1     = (const float*)d_in[8];
    const float* beta1  = (const float*)d_in[9];
    const float* g2     = (const float*)d_in[10];
    const float* beta2  = (const float*)d_in[11];
    const float* Wc     = (const float*)d_in[12];
    const float* bc     = (const float*)d_in[13];
    float* outp = (float*)d_out;

    // workspace layout (bf16 residual stream; NSPLIT=2; w2t holds all 4 layers; pacc bf16)
    __bf16* xbuf = (__bf16*)d_ws;                                      // BS_*E_ bf16
    __hip_bfloat16* qbf = (__hip_bfloat16*)(xbuf + (size_t)BS_ * E_);  // BS_*E_ bf16
    __hip_bfloat16* qT  = qbf + (size_t)BS_ * E_;                      // BS_*E_ bf16
    __hip_bfloat16* w2t = qT + (size_t)BS_ * E_;                       // 4*E_*FF_ bf16
    float* psum  = (float*)(w2t + (size_t)4 * E_ * FF_);               // 16*8*E_ f32
    float* xmean = psum + 16 * 8 * E_;                                 // B_*E_ f32
    float* pl    = xmean + B_ * E_;                                    // NSPLIT*BS_ f32
    __bf16* pacc = (__bf16*)(pl + (size_t)NSPLIT * BS_);               // NSPLIT*BS_*E_ bf16

    k_embed<<<BS_, 256, 0, stream>>>(tokens, emb, xbuf);
    for (int l = 0; l < 4; l++)      // layer-static: hoisted out of the layer loop
        k_w2t<<<dim3(FF_ / 64, E_ / 64), 256, 0, stream>>>(W2 + (size_t)l * FF_ * E_,
                                                           w2t + (size_t)l * E_ * FF_);

    // layer 0's q from the standalone pass; layers 1..3 get q from k_ffn's fused epilogue
    k_qt<<<dim3(S_ / 64, E_ / 64, B_), 256, 0, stream>>>(xbuf, phi, qbf, qT);

    for (int l = 0; l < 4; l++) {
        k_attn<<<(S_ / 64) * B_ * NSPLIT, 256, 0, stream>>>(qbf, qT, pacc, pl);
        k_aln<<<BS_ / 4, 256, 0, stream>>>(pacc, pl, xbuf, g1 + l * E_, beta1 + l * E_);
        int gen_q = (l < 3) ? 1 : 0;
        const float* phn = phi + (size_t)(gen_q ? (l + 1) : 0) * NQ_;
        k_ffn<<<BS_ / 32, 256, 0, stream>>>(xbuf, theta + l * NQ_,
                                            W1 + (size_t)l * NQ_ * FF_, b1 + (size_t)l * FF_,
                                            w2t + (size_t)l * E_ * FF_, b2 + (size_t)l * E_,
                                            g2 + l * E_, beta2 + l * E_,
                                            phn, (__bf16*)qbf, (__bf16*)qT, gen_q);
    }

    k_mean<<<dim3(16, B_), 256, 0, stream>>>(xbuf, psum);
    k_mean2<<<8, 256, 0, stream>>>(psum, xmean);
    k_cls<<<1, 128, 0, stream>>>(xmean, Wc, bc, outp);
}

// Round 25
// 407.753 us; speedup vs baseline: 1.1165x; 1.0323x over previous
//
#include <hip/hip_runtime.h>
#include <hip/hip_bf16.h>

#define B_ 8
#define S_ 2048
#define E_ 256
#define FF_ 1024
#define NQ_ 8
#define NC_ 10
#define BS_ (B_*S_)
#define NSPLIT 2
#define KVBLK 32

typedef __bf16 bf16x8 __attribute__((ext_vector_type(8)));
typedef __bf16 bf16x4 __attribute__((ext_vector_type(4)));
typedef float f32x4 __attribute__((ext_vector_type(4)));

#define MFMA16(a,b,c) __builtin_amdgcn_mfma_f32_16x16x32_bf16(a,b,c,0,0,0)

// ---------------- fused embed + PE + layer-0 q-compute + transpose ----------------
// q for head h depends only on x[8h..8h+7] (e-local): compute embed tile in f32,
// write x (bf16) and q0 (from pre-rounding f32 — closer to f32 reference).
__global__ __launch_bounds__(256) void k_embqt(const int* __restrict__ tokens,
                                               const float* __restrict__ emb,
                                               const float* __restrict__ phi_l,
                                               __bf16* __restrict__ x,
                                               __bf16* __restrict__ qbf,
                                               __bf16* __restrict__ qT) {
    __shared__ __align__(16) __bf16 tile[64][76];
    int t0 = blockIdx.x * 64, e0 = blockIdx.y * 64, b = blockIdx.z;
    int tid = threadIdx.x;
    float ph[8];
#pragma unroll
    for (int j = 0; j < 8; j++) ph[j] = phi_l[j];
#pragma unroll
    for (int k = 0; k < 2; k++) {
        int idx = k * 256 + tid;
        int r = idx >> 3, hh = idx & 7;           // row-local, head-slot (8 e each)
        int s = t0 + r;                           // sequence position
        int tok = tokens[(size_t)b * S_ + t0 + r];
        const float* ep = emb + (size_t)tok * E_ + e0 + hh * 8;
        f32x4 v0 = *(const f32x4*)ep;
        f32x4 v1 = *(const f32x4*)(ep + 4);
        float xv[8];
#pragma unroll
        for (int j = 0; j < 8; j++) {
            int e = e0 + hh * 8 + j;
            int i2 = e & ~1;
            float d = __expf((float)i2 * (-9.210340371976184f / 256.0f));
            float ang = (float)s * d;
            float pe = (e & 1) ? __cosf(ang) : __sinf(ang);
            xv[j] = ((j < 4) ? v0[j] : v1[j - 4]) + pe;
        }
        bf16x8 xb;
#pragma unroll
        for (int j = 0; j < 8; j++) xb[j] = (__bf16)xv[j];
        *(bf16x8*)(x + ((size_t)b * S_ + t0 + r) * E_ + e0 + hh * 8) = xb;
        // ---- q from f32 x ----
        float c[8];
#pragma unroll
        for (int j = 0; j < 8; j++) c[j] = __cosf(xv[j] + ph[j]);
        float q[8];
        float run = c[0];
#pragma unroll
        for (int i = 1; i < 8; i++) { run *= c[i]; q[i] = run; }
        float o0 = c[1];
#pragma unroll
        for (int i = 2; i < 8; i++) o0 *= c[i];
        q[0] = o0;
        bf16x8 v;
#pragma unroll
        for (int j = 0; j < 8; j++) v[j] = (__bf16)q[j];
        *(bf16x8*)(qbf + ((size_t)b * S_ + t0 + r) * E_ + e0 + hh * 8) = v;
        *(bf16x8*)&tile[r][hh * 8] = v;
    }
    __syncthreads();
#pragma unroll
    for (int k = 0; k < 2; k++) {
        int idx = k * 256 + tid;
        int el = idx >> 3, tc = idx & 7;          // e-local, t-chunk
        bf16x8 v;
#pragma unroll
        for (int j = 0; j < 8; j++) v[j] = tile[tc * 8 + j][el];
        *(bf16x8*)(qT + ((size_t)b * E_ + e0 + el) * S_ + t0 + tc * 8) = v;
    }
}

// ---------------- flash attention: Wq=32, KVBLK=32, K+V via global_load_lds, vtile dbuf ----------------
// p = exp(s - 44): |s| <= 90.5, diag s_ii >= 0 => no overflow, row-sum >= e^-44.
// Mathematically identical to softmax. 1D grid 512: b = bid&7 (batch->XCD pin).
// R20/R22-measured best (58us): shared-P 32qx128e, 2 barriers/iter. FROZEN.
__global__ __launch_bounds__(256, 2) void k_attn(const __hip_bfloat16* __restrict__ qbf,
                                                 const __hip_bfloat16* __restrict__ qT,
                                                 __bf16* __restrict__ pacc,
                                                 float* __restrict__ pl) {
    __shared__ __align__(16) __bf16 ktile[KVBLK * 256];     // 16KB [kv32][e256], chunk ^= r&7
    __shared__ __align__(16) __bf16 vtile[2][256 * KVBLK];  // 2x16KB [e][kv32], chunk ^= (e>>1)&3
    __shared__ __align__(16) __bf16 plds[2][32][36];        // 4.6KB [rg][q32][kv32+4] (18-word rows)
    __shared__ float redl[2][32][2];
    const float SCALE = 0.3535533905932738f;                // 1/sqrt(8)
    int bid  = blockIdx.x;
    int b    = bid & 7;                                     // batch == XCD
    int qt   = (bid >> 3) & 31;
    int z    = bid >> 8;
    int tid  = threadIdx.x;
    int wv   = tid >> 6;
    int lane = tid & 63;
    int r16  = lane & 15;
    int kg   = lane >> 4;
    int rg   = wv >> 1, eh = wv & 1;
    int qrow0 = qt * 64 + rg * 32;
    int ebase = eh * 128;

    bf16x8 aq[2][8];
#pragma unroll
    for (int qs = 0; qs < 2; qs++)
#pragma unroll
        for (int kk = 0; kk < 8; kk++)
            aq[qs][kk] = *(const bf16x8*)(qbf + ((size_t)b * S_ + qrow0 + qs * 16 + r16) * E_ + kk * 32 + kg * 8);

    f32x4 acc0[8], acc1[8];
#pragma unroll
    for (int cf = 0; cf < 8; cf++) { acc0[cf] = (f32x4){0.f,0.f,0.f,0.f}; acc1[cf] = (f32x4){0.f,0.f,0.f,0.f}; }
    float lrow0[4] = {0.f,0.f,0.f,0.f}, lrow1[4] = {0.f,0.f,0.f,0.f};

    constexpr int SPAN = S_ / NSPLIT;
    constexpr int NT = SPAN / KVBLK;    // 32
    int k0 = z * SPAN;

    auto issue_k = [&](int kb) {
#pragma unroll
        for (int c = 0; c < 4; c++) {
            int seg = wv * 4 + c;                       // 16 x 1KB segments (32 rows x 512B)
            int r = seg * 2 + (lane >> 5);
            int ch = lane & 31;
            const __hip_bfloat16* src = qbf + ((size_t)b * S_ + kb + r) * E_ + ((ch ^ (r & 7)) * 8);
            __builtin_amdgcn_global_load_lds((const __attribute__((address_space(1))) void*)src,
                                             (__attribute__((address_space(3))) void*)(ktile + seg * 512),
                                             16, 0, 0);
        }
    };
    auto issue_v = [&](int kb, int buf) {
#pragma unroll
        for (int c = 0; c < 4; c++) {
            int seg = wv * 4 + c;                       // 16 x 1KB segments (16 e-rows x 64B each)
            int e = seg * 16 + (lane >> 2);
            int ch = lane & 3;
            const __hip_bfloat16* src = qT + ((size_t)b * E_ + e) * S_ + kb + ((ch ^ ((e >> 1) & 3)) * 8);
            __builtin_amdgcn_global_load_lds((const __attribute__((address_space(1))) void*)src,
                                             (__attribute__((address_space(3))) void*)(&vtile[buf][seg * 512]),
                                             16, 0, 0);
        }
    };

    // prologue: tile 0
    issue_k(k0);
    issue_v(k0, 0);
    asm volatile("s_waitcnt vmcnt(0)" ::: "memory");
    __syncthreads();

    for (int kt = 0; kt < NT; kt++) {
        int vcur = kt & 1;
        // ---- QK^T: this wave's kv-half [eh*16, eh*16+16) ----
        f32x4 s0 = (f32x4){0.f,0.f,0.f,0.f}, s1 = (f32x4){0.f,0.f,0.f,0.f};
#pragma unroll
        for (int kk = 0; kk < 8; kk++) {
            bf16x8 bk = *(const bf16x8*)&ktile[(eh * 16 + r16) * 256 + (((kk * 4 + kg) ^ (r16 & 7)) * 8)];
            s0 = MFMA16(aq[0][kk], bk, s0);
            s1 = MFMA16(aq[1][kk], bk, s1);
        }
#pragma unroll
        for (int i = 0; i < 4; i++) {
            float p0 = __expf(fmaf(s0[i], SCALE, -44.0f));
            float p1 = __expf(fmaf(s1[i], SCALE, -44.0f));
            plds[rg][kg * 4 + i][eh * 16 + r16]      = (__bf16)p0;
            plds[rg][16 + kg * 4 + i][eh * 16 + r16] = (__bf16)p1;
            lrow0[i] += p0;
            lrow1[i] += p1;
        }
        __syncthreads();                         // B2: P complete; ktile/vtile[vcur^1] reads done
        bool more = (kt + 1 < NT);
        if (more) {                              // async into ktile + vtile[vcur^1]; lands under PV
            int kn = k0 + (kt + 1) * KVBLK;
            issue_k(kn);
            issue_v(kn, vcur ^ 1);
        }
        // ---- PV ----
        bf16x8 pa0 = *(const bf16x8*)&plds[rg][r16][kg * 8];
        bf16x8 pa1 = *(const bf16x8*)&plds[rg][16 + r16][kg * 8];
#pragma unroll
        for (int cf = 0; cf < 8; cf++) {
            int vrow = ebase + cf * 16 + r16;
            bf16x8 bv = *(const bf16x8*)&vtile[vcur][vrow * KVBLK + ((kg ^ ((vrow >> 1) & 3)) * 8)];
            acc0[cf] = MFMA16(pa0, bv, acc0[cf]);
            acc1[cf] = MFMA16(pa1, bv, acc1[cf]);
        }
        if (more) {
            asm volatile("s_waitcnt vmcnt(0)" ::: "memory");
            __syncthreads();                     // B1: all waves' loads landed
        }
    }

    // ---- epilogue: l totals then partial writes (bf16) ----
#pragma unroll
    for (int i = 0; i < 4; i++) {
#pragma unroll
        for (int m = 1; m <= 8; m <<= 1) {
            lrow0[i] += __shfl_xor(lrow0[i], m);
            lrow1[i] += __shfl_xor(lrow1[i], m);
        }
    }
    if (r16 == 0) {
#pragma unroll
        for (int i = 0; i < 4; i++) {
            redl[rg][kg * 4 + i][eh]      = lrow0[i];
            redl[rg][16 + kg * 4 + i][eh] = lrow1[i];
        }
    }
    __syncthreads();
    size_t prow0 = (size_t)z * BS_ + (size_t)b * S_ + qrow0;
    if (eh == 0 && r16 == 0) {
#pragma unroll
        for (int i = 0; i < 4; i++) {
            int q = kg * 4 + i;
            pl[prow0 + q]      = redl[rg][q][0] + redl[rg][q][1];
            pl[prow0 + 16 + q] = redl[rg][16 + q][0] + redl[rg][16 + q][1];
        }
    }
#pragma unroll
    for (int i = 0; i < 4; i++) {
#pragma unroll
        for (int cf = 0; cf < 8; cf++) {
            pacc[(prow0 + kg * 4 + i) * E_ + ebase + cf * 16 + r16]      = (__bf16)acc0[cf][i];
            pacc[(prow0 + 16 + kg * 4 + i) * E_ + ebase + cf * 16 + r16] = (__bf16)acc1[cf][i];
        }
    }
}

// ---------------- fused merge (2 bf16 partials) + residual + layernorm (bf16 x) ----------------
__global__ __launch_bounds__(256) void k_aln(const __bf16* __restrict__ pacc,
                                             const float* __restrict__ pl,
                                             __bf16* __restrict__ x,
                                             const float* __restrict__ g,
                                             const float* __restrict__ bb) {
    int wv = threadIdx.x >> 6, lane = threadIdx.x & 63;
    size_t row = (size_t)blockIdx.x * 4 + wv;
    float inv = 1.0f / (pl[row] + pl[BS_ + row]);
    bf16x4 a0 = ((const bf16x4*)(pacc + row * E_))[lane];
    bf16x4 a1 = ((const bf16x4*)(pacc + (size_t)BS_ * E_ + row * E_))[lane];
    bf16x4 xv = ((const bf16x4*)(x + row * E_))[lane];
    f32x4 v;
    float s = 0.f, sq = 0.f;
#pragma unroll
    for (int j = 0; j < 4; j++) {
        v[j] = (float)xv[j] + ((float)a0[j] + (float)a1[j]) * inv;
        s += v[j]; sq += v[j] * v[j];
    }
#pragma unroll
    for (int m = 1; m <= 32; m <<= 1) { s += __shfl_xor(s, m); sq += __shfl_xor(sq, m); }
    float mean = s * (1.f / E_);
    float var = sq * (1.f / E_) - mean * mean;
    float rstd = rsqrtf(var + 1e-5f);
    f32x4 gv = ((const f32x4*)g)[lane];
    f32x4 bv = ((const f32x4*)bb)[lane];
    bf16x4 o;
#pragma unroll
    for (int j = 0; j < 4; j++) o[j] = (__bf16)((v[j] - mean) * rstd * gv[j] + bv[j]);
    ((bf16x4*)(x + row * E_))[lane] = o;
}

// ---------------- W2 transpose to bf16 (tiled, all 4 layers in z) ----------------
__global__ __launch_bounds__(256) void k_w2t(const float* __restrict__ W2,
                                             __hip_bfloat16* __restrict__ w2t) {
    __shared__ __align__(16) __bf16 tile[64][72];
    int k0 = blockIdx.x * 64, e0 = blockIdx.y * 64, l = blockIdx.z;
    const float* W2l = W2 + (size_t)l * FF_ * E_;
    __hip_bfloat16* w2tl = w2t + (size_t)l * E_ * FF_;
    int tid = threadIdx.x;
#pragma unroll
    for (int half = 0; half < 2; half++) {
        int r  = half * 32 + (tid >> 3);      // k row
        int c8 = (tid & 7) * 8;               // e offset
        f32x4 v0 = *(const f32x4*)(W2l + (size_t)(k0 + r) * E_ + e0 + c8);
        f32x4 v1 = *(const f32x4*)(W2l + (size_t)(k0 + r) * E_ + e0 + c8 + 4);
#pragma unroll
        for (int j = 0; j < 4; j++) { tile[r][c8 + j] = (__bf16)v0[j]; tile[r][c8 + 4 + j] = (__bf16)v1[j]; }
    }
    __syncthreads();
#pragma unroll
    for (int half = 0; half < 2; half++) {
        int e  = half * 32 + (tid >> 3);
        int k8 = (tid & 7) * 8;
        bf16x8 v;
#pragma unroll
        for (int j = 0; j < 8; j++) v[j] = tile[k8 + j][e];
        *(bf16x8*)(w2tl + (size_t)(e0 + e) * FF_ + k0 + k8) = v;
    }
}

// ---------------- fused FFN: rank-8 h + GEMM + bias + residual + LN + q-gen for next layer ----------------
__global__ __launch_bounds__(256) void k_ffn(__bf16* __restrict__ x,
                                             const float* __restrict__ theta_l,
                                             const float* __restrict__ W1l,
                                             const float* __restrict__ b1l,
                                             const __hip_bfloat16* __restrict__ w2t,
                                             const float* __restrict__ b2l,
                                             const float* __restrict__ g,
                                             const float* __restrict__ bb,
                                             const float* __restrict__ phi_next,
                                             __bf16* __restrict__ qbf,
                                             __bf16* __restrict__ qT,
                                             int gen_q) {
    __shared__ __align__(16) __bf16 Bld[2][256 * 64];   // [buf][e][k64] linear (global_load_lds dest)
    __shared__ __align__(16) __bf16 Ald[2][32 * 64];    // [buf][r][k64], chunk ^= r&7
    __shared__ float qmld[32][9];
    __shared__ float reds[32][4][2];
    int tid = threadIdx.x;
    int wv = tid >> 6, lane = tid & 63;
    int r16 = lane & 15, kg = lane >> 4;
    int rbase = blockIdx.x * 32;
    int ebQ = wv * 64;
    const int NT = FF_ / 64;   // 16

    {   // qm[r][i] = cos(x[row][i]) * cos(theta[i])
        int r = tid >> 3, i = tid & 7;
        qmld[r][i] = __cosf((float)x[(size_t)(rbase + r) * E_ + i]) * __cosf(theta_l[i]);
    }

    f32x4 w[18];   // W1 chunk (16) + b1 chunk (2), all constant-indexed

    auto issue_B = [&](int kt, int buf) {
#pragma unroll
        for (int s = 0; s < 8; s++) {
            int seg = wv * 8 + s;                       // 32 x 1KB segments
            int e = seg * 8 + (lane >> 3);
            int c = lane & 7;
            const __hip_bfloat16* src = w2t + (size_t)e * FF_ + kt * 64 + ((c ^ (e & 7)) * 8);
            __builtin_amdgcn_global_load_lds((const __attribute__((address_space(1))) void*)src,
                                             (__attribute__((address_space(3))) void*)(&Bld[buf][seg * 512]),
                                             16, 0, 0);
        }
    };
    auto load_W1 = [&](int kt) {
        int c = tid & 7;
        int k = kt * 64 + c * 8;
#pragma unroll
        for (int i = 0; i < 8; i++) {
            w[2 * i]     = *(const f32x4*)(W1l + (size_t)i * FF_ + k);
            w[2 * i + 1] = *(const f32x4*)(W1l + (size_t)i * FF_ + k + 4);
        }
        w[16] = *(const f32x4*)(b1l + k);
        w[17] = *(const f32x4*)(b1l + k + 4);
    };
    auto math_h = [&](int buf) {
        int r = tid >> 3, c = tid & 7;
        f32x4 h0 = w[16], h1 = w[17];
#pragma unroll
        for (int i = 0; i < 8; i++) {
            float qv = qmld[r][i];
#pragma unroll
            for (int j = 0; j < 4; j++) {
                h0[j] = fmaf(qv, w[2 * i][j], h0[j]);
                h1[j] = fmaf(qv, w[2 * i + 1][j], h1[j]);
            }
        }
        bf16x8 hv;
#pragma unroll
        for (int j = 0; j < 4; j++) {
            hv[j]     = (__bf16)fmaxf(h0[j], 0.f);
            hv[4 + j] = (__bf16)fmaxf(h1[j], 0.f);
        }
        *(bf16x8*)&Ald[buf][r * 64 + ((c ^ (r & 7)) * 8)] = hv;
    };

    // prologue
    issue_B(0, 0);
    load_W1(0);
    __syncthreads();          // qmld visible; B(0) drained
    math_h(0);
    __syncthreads();          // Ald[0] visible

    f32x4 acc[2][4];
#pragma unroll
    for (int qs = 0; qs < 2; qs++)
#pragma unroll
        for (int cf = 0; cf < 4; cf++) acc[qs][cf] = (f32x4){0.f, 0.f, 0.f, 0.f};

    for (int kt = 0; kt < NT; kt++) {
        int cur = kt & 1;
        bool more = (kt + 1 < NT);
        if (more) {
            issue_B(kt + 1, cur ^ 1);   // in flight across MFMA phase
            load_W1(kt + 1);            // reg prefetch, consumed after MFMA
        }
        bf16x8 aq[2][2];
#pragma unroll
        for (int qs = 0; qs < 2; qs++)
#pragma unroll
            for (int kk = 0; kk < 2; kk++)
                aq[qs][kk] = *(const bf16x8*)&Ald[cur][(qs * 16 + r16) * 64 + (((kk * 4 + kg) ^ (r16 & 7)) * 8)];
#pragma unroll
        for (int cf = 0; cf < 4; cf++) {
            int e = ebQ + cf * 16 + r16;
#pragma unroll
            for (int kk = 0; kk < 2; kk++) {
                bf16x8 bv = *(const bf16x8*)&Bld[cur][e * 64 + (((kk * 4 + kg) ^ (e & 7)) * 8)];
                acc[0][cf] = MFMA16(aq[0][kk], bv, acc[0][cf]);
                acc[1][cf] = MFMA16(aq[1][kk], bv, acc[1][cf]);
            }
        }
        if (more) {
            math_h(cur ^ 1);            // W1 regs already resident
            __syncthreads();            // drains B(kt+1) + Ald writes; guards buf reuse
        }
    }

    // epilogue: bias + residual + layernorm
    float sA[2][4] = {{0.f,0.f,0.f,0.f},{0.f,0.f,0.f,0.f}};
    float sQ[2][4] = {{0.f,0.f,0.f,0.f},{0.f,0.f,0.f,0.f}};
#pragma unroll
    for (int qs = 0; qs < 2; qs++)
#pragma unroll
        for (int cf = 0; cf < 4; cf++) {
            int e = ebQ + cf * 16 + r16;
            float b2v = b2l[e];
#pragma unroll
            for (int i = 0; i < 4; i++) {
                size_t orow = (size_t)rbase + qs * 16 + kg * 4 + i;
                float t = acc[qs][cf][i] + b2v + (float)x[orow * E_ + e];
                acc[qs][cf][i] = t;
                sA[qs][i] += t; sQ[qs][i] += t * t;
            }
        }
#pragma unroll
    for (int qs = 0; qs < 2; qs++)
#pragma unroll
        for (int i = 0; i < 4; i++) {
#pragma unroll
            for (int m = 1; m <= 8; m <<= 1) {
                sA[qs][i] += __shfl_xor(sA[qs][i], m);
                sQ[qs][i] += __shfl_xor(sQ[qs][i], m);
            }
        }
    if (r16 == 0) {
#pragma unroll
        for (int qs = 0; qs < 2; qs++)
#pragma unroll
            for (int i = 0; i < 4; i++) {
                int row = qs * 16 + kg * 4 + i;
                reds[row][wv][0] = sA[qs][i];
                reds[row][wv][1] = sQ[qs][i];
            }
    }
    __syncthreads();
    float mean[2][4], rstd[2][4];
#pragma unroll
    for (int qs = 0; qs < 2; qs++)
#pragma unroll
        for (int i = 0; i < 4; i++) {
            int row = qs * 16 + kg * 4 + i;
            float S = reds[row][0][0] + reds[row][1][0] + reds[row][2][0] + reds[row][3][0];
            float Q = reds[row][0][1] + reds[row][1][1] + reds[row][2][1] + reds[row][3][1];
            mean[qs][i] = S * (1.f / E_);
            float var = Q * (1.f / E_) - mean[qs][i] * mean[qs][i];
            rstd[qs][i] = rsqrtf(var + 1e-5f);
        }
    // final x1 (keep in acc for q-gen) + store
#pragma unroll
    for (int qs = 0; qs < 2; qs++)
#pragma unroll
        for (int cf = 0; cf < 4; cf++) {
            int e = ebQ + cf * 16 + r16;
            float gv = g[e], bv = bb[e];
#pragma unroll
            for (int i = 0; i < 4; i++) {
                size_t orow = (size_t)rbase + qs * 16 + kg * 4 + i;
                float xn = (acc[qs][cf][i] - mean[qs][i]) * rstd[qs][i] * gv + bv;
                acc[qs][cf][i] = xn;
                x[orow * E_ + e] = (__bf16)xn;
            }
        }
    // q-gen for next layer: per 8-lane head group product scans (no division)
    if (gen_q) {
        int bq = rbase / S_;
        int trow0 = rbase % S_;
        float ph = phi_next[r16 & 7];
        int hp = r16 & 7;
#pragma unroll
        for (int qs = 0; qs < 2; qs++)
#pragma unroll
            for (int cf = 0; cf < 4; cf++) {
                int e = ebQ + cf * 16 + r16;
#pragma unroll
                for (int i = 0; i < 4; i++) {
                    float c = __cosf(acc[qs][cf][i] + ph);
                    float scan = c;                         // incl prefix prod of c
                    float cp = (hp == 0) ? 1.f : c;         // same with c0 := 1
#pragma unroll
                    for (int d = 1; d <= 4; d <<= 1) {
                        float t1 = __shfl_up(scan, d, 8);
                        float t2 = __shfl_up(cp, d, 8);
                        if (hp >= d) { scan *= t1; cp *= t2; }
                    }
                    float q0 = __shfl(cp, 7, 8);            // prod c1..c7
                    float qv = (hp == 0) ? q0 : scan;
                    int trow = trow0 + qs * 16 + kg * 4 + i;
                    __bf16 qb = (__bf16)qv;
                    qbf[((size_t)bq * S_ + trow) * E_ + e] = qb;
                    qT[((size_t)bq * E_ + e) * S_ + trow]  = qb;
                }
            }
    }
}

// ---------------- mean over S (two-stage, deterministic; bf16 x) ----------------
__global__ __launch_bounds__(256) void k_mean(const __bf16* __restrict__ x, float* __restrict__ psum) {
    int c = blockIdx.x, b = blockIdx.y, e = threadIdx.x;
    float s = 0.f;
    size_t base = ((size_t)b * S_ + c * 128) * E_ + e;
    for (int r = 0; r < 128; r++) s += (float)x[base + (size_t)r * E_];
    psum[(c * 8 + b) * E_ + e] = s;
}

__global__ __launch_bounds__(256) void k_mean2(const float* __restrict__ psum, float* __restrict__ xmean) {
    int idx = blockIdx.x * 256 + threadIdx.x;   // 0..2047 -> (b,e)
    int b = idx >> 8, e = idx & 255;
    float s = 0.f;
    for (int c = 0; c < 16; c++) s += psum[(c * 8 + b) * E_ + e];
    xmean[idx] = s * (1.f / S_);
}

// ---------------- classifier ----------------
__global__ __launch_bounds__(128) void k_cls(const float* __restrict__ xmean,
                                             const float* __restrict__ Wc,
                                             const float* __restrict__ bc,
                                             float* __restrict__ outp) {
    int t = threadIdx.x;
    if (t >= B_ * NC_) return;
    int b = t / NC_, c = t % NC_;
    float s = bc[c];
    for (int e = 0; e < E_; e++) s += xmean[b * E_ + e] * Wc[e * NC_ + c];
    outp[t] = s;
}

extern "C" void kernel_launch(void* const* d_in, const int* in_sizes, int n_in,
                              void* d_out, int out_size, void* d_ws, size_t ws_size,
                              hipStream_t stream) {
    (void)in_sizes; (void)n_in; (void)out_size; (void)ws_size;
    const int*   tokens = (const int*)d_in[0];
    const float* emb    = (const float*)d_in[1];
    const float* phi    = (const float*)d_in[2];
    const float* theta  = (const float*)d_in[3];
    const float* W1     = (const float*)d_in[4];
    const float* b1     = (const float*)d_in[5];
    const float* W2     = (const float*)d_in[6];
    const float* b2     = (const float*)d_in[7];
    const float* g1     = (const float*)d_in[8];
    const float* beta1  = (const float*)d_in[9];
    const float* g2     = (const float*)d_in[10];
    const float* beta2  = (const float*)d_in[11];
    const float* Wc     = (const float*)d_in[12];
    const float* bc     = (const float*)d_in[13];
    float* outp = (float*)d_out;

    // workspace layout (bf16 residual stream; NSPLIT=2; w2t holds all 4 layers; pacc bf16)
    __bf16* xbuf = (__bf16*)d_ws;                                      // BS_*E_ bf16
    __hip_bfloat16* qbf = (__hip_bfloat16*)(xbuf + (size_t)BS_ * E_);  // BS_*E_ bf16
    __hip_bfloat16* qT  = qbf + (size_t)BS_ * E_;                      // BS_*E_ bf16
    __hip_bfloat16* w2t = qT + (size_t)BS_ * E_;                       // 4*E_*FF_ bf16
    float* psum  = (float*)(w2t + (size_t)4 * E_ * FF_);               // 16*8*E_ f32
    float* xmean = psum + 16 * 8 * E_;                                 // B_*E_ f32
    float* pl    = xmean + B_ * E_;                                    // NSPLIT*BS_ f32
    __bf16* pacc = (__bf16*)(pl + (size_t)NSPLIT * BS_);               // NSPLIT*BS_*E_ bf16

    k_w2t<<<dim3(FF_ / 64, E_ / 64, 4), 256, 0, stream>>>(W2, w2t);
    // fused embed + PE + layer-0 q; layers 1..3 get q from k_ffn's fused epilogue
    k_embqt<<<dim3(S_ / 64, E_ / 64, B_), 256, 0, stream>>>(tokens, emb, phi,
                                                            xbuf, (__bf16*)qbf, (__bf16*)qT);

    for (int l = 0; l < 4; l++) {
        k_attn<<<(S_ / 64) * B_ * NSPLIT, 256, 0, stream>>>(qbf, qT, pacc, pl);
        k_aln<<<BS_ / 4, 256, 0, stream>>>(pacc, pl, xbuf, g1 + l * E_, beta1 + l * E_);
        int gen_q = (l < 3) ? 1 : 0;
        const float* phn = phi + (size_t)(gen_q ? (l + 1) : 0) * NQ_;
        k_ffn<<<BS_ / 32, 256, 0, stream>>>(xbuf, theta + l * NQ_,
                                            W1 + (size_t)l * NQ_ * FF_, b1 + (size_t)l * FF_,
                                            w2t + (size_t)l * E_ * FF_, b2 + (size_t)l * E_,
                                            g2 + l * E_, beta2 + l * E_,
                                            phn, (__bf16*)qbf, (__bf16*)qT, gen_q);
    }

    k_mean<<<dim3(16, B_), 256, 0, stream>>>(xbuf, psum);
    k_mean2<<<8, 256, 0, stream>>>(psum, xmean);
    k_cls<<<1, 128, 0, stream>>>(xmean, Wc, bc, outp);
}

// Round 26
// 401.304 us; speedup vs baseline: 1.1344x; 1.0161x over previous
//
#include <hip/hip_runtime.h>
#include <hip/hip_bf16.h>

#define B_ 8
#define S_ 2048
#define E_ 256
#define FF_ 1024
#define NQ_ 8
#define NC_ 10
#define BS_ (B_*S_)
#define NSPLIT 2
#define KVBLK 32

typedef __bf16 bf16x8 __attribute__((ext_vector_type(8)));
typedef __bf16 bf16x4 __attribute__((ext_vector_type(4)));
typedef float f32x4 __attribute__((ext_vector_type(4)));

#define MFMA16(a,b,c) __builtin_amdgcn_mfma_f32_16x16x32_bf16(a,b,c,0,0,0)

// ---------------- fused embed + PE + layer-0 q-compute + transpose ----------------
__global__ __launch_bounds__(256) void k_embqt(const int* __restrict__ tokens,
                                               const float* __restrict__ emb,
                                               const float* __restrict__ phi_l,
                                               __bf16* __restrict__ x,
                                               __bf16* __restrict__ qbf,
                                               __bf16* __restrict__ qT) {
    __shared__ __align__(16) __bf16 tile[64][76];
    int t0 = blockIdx.x * 64, e0 = blockIdx.y * 64, b = blockIdx.z;
    int tid = threadIdx.x;
    float ph[8];
#pragma unroll
    for (int j = 0; j < 8; j++) ph[j] = phi_l[j];
#pragma unroll
    for (int k = 0; k < 2; k++) {
        int idx = k * 256 + tid;
        int r = idx >> 3, hh = idx & 7;           // row-local, head-slot (8 e each)
        int s = t0 + r;                           // sequence position
        int tok = tokens[(size_t)b * S_ + t0 + r];
        const float* ep = emb + (size_t)tok * E_ + e0 + hh * 8;
        f32x4 v0 = *(const f32x4*)ep;
        f32x4 v1 = *(const f32x4*)(ep + 4);
        float xv[8];
#pragma unroll
        for (int j = 0; j < 8; j++) {
            int e = e0 + hh * 8 + j;
            int i2 = e & ~1;
            float d = __expf((float)i2 * (-9.210340371976184f / 256.0f));
            float ang = (float)s * d;
            float pe = (e & 1) ? __cosf(ang) : __sinf(ang);
            xv[j] = ((j < 4) ? v0[j] : v1[j - 4]) + pe;
        }
        bf16x8 xb;
#pragma unroll
        for (int j = 0; j < 8; j++) xb[j] = (__bf16)xv[j];
        *(bf16x8*)(x + ((size_t)b * S_ + t0 + r) * E_ + e0 + hh * 8) = xb;
        // ---- q from f32 x ----
        float c[8];
#pragma unroll
        for (int j = 0; j < 8; j++) c[j] = __cosf(xv[j] + ph[j]);
        float q[8];
        float run = c[0];
#pragma unroll
        for (int i = 1; i < 8; i++) { run *= c[i]; q[i] = run; }
        float o0 = c[1];
#pragma unroll
        for (int i = 2; i < 8; i++) o0 *= c[i];
        q[0] = o0;
        bf16x8 v;
#pragma unroll
        for (int j = 0; j < 8; j++) v[j] = (__bf16)q[j];
        *(bf16x8*)(qbf + ((size_t)b * S_ + t0 + r) * E_ + e0 + hh * 8) = v;
        *(bf16x8*)&tile[r][hh * 8] = v;
    }
    __syncthreads();
#pragma unroll
    for (int k = 0; k < 2; k++) {
        int idx = k * 256 + tid;
        int el = idx >> 3, tc = idx & 7;          // e-local, t-chunk
        bf16x8 v;
#pragma unroll
        for (int j = 0; j < 8; j++) v[j] = tile[tc * 8 + j][el];
        *(bf16x8*)(qT + ((size_t)b * E_ + e0 + el) * S_ + t0 + tc * 8) = v;
    }
}

// ---------------- flash attention: Wq=32, KVBLK=32, K+V via global_load_lds, vtile dbuf ----------------
// p = exp(s - 44): |s| <= 90.5, diag s_ii >= 0 => no overflow, row-sum >= e^-44.
// Mathematically identical to softmax. 1D grid 512: b = bid&7 (batch->XCD pin).
// R20/R22-measured best (58us): shared-P 32qx128e, 2 barriers/iter. FROZEN.
__global__ __launch_bounds__(256, 2) void k_attn(const __hip_bfloat16* __restrict__ qbf,
                                                 const __hip_bfloat16* __restrict__ qT,
                                                 __bf16* __restrict__ pacc,
                                                 float* __restrict__ pl) {
    __shared__ __align__(16) __bf16 ktile[KVBLK * 256];     // 16KB [kv32][e256], chunk ^= r&7
    __shared__ __align__(16) __bf16 vtile[2][256 * KVBLK];  // 2x16KB [e][kv32], chunk ^= (e>>1)&3
    __shared__ __align__(16) __bf16 plds[2][32][36];        // 4.6KB [rg][q32][kv32+4] (18-word rows)
    __shared__ float redl[2][32][2];
    const float SCALE = 0.3535533905932738f;                // 1/sqrt(8)
    int bid  = blockIdx.x;
    int b    = bid & 7;                                     // batch == XCD
    int qt   = (bid >> 3) & 31;
    int z    = bid >> 8;
    int tid  = threadIdx.x;
    int wv   = tid >> 6;
    int lane = tid & 63;
    int r16  = lane & 15;
    int kg   = lane >> 4;
    int rg   = wv >> 1, eh = wv & 1;
    int qrow0 = qt * 64 + rg * 32;
    int ebase = eh * 128;

    bf16x8 aq[2][8];
#pragma unroll
    for (int qs = 0; qs < 2; qs++)
#pragma unroll
        for (int kk = 0; kk < 8; kk++)
            aq[qs][kk] = *(const bf16x8*)(qbf + ((size_t)b * S_ + qrow0 + qs * 16 + r16) * E_ + kk * 32 + kg * 8);

    f32x4 acc0[8], acc1[8];
#pragma unroll
    for (int cf = 0; cf < 8; cf++) { acc0[cf] = (f32x4){0.f,0.f,0.f,0.f}; acc1[cf] = (f32x4){0.f,0.f,0.f,0.f}; }
    float lrow0[4] = {0.f,0.f,0.f,0.f}, lrow1[4] = {0.f,0.f,0.f,0.f};

    constexpr int SPAN = S_ / NSPLIT;
    constexpr int NT = SPAN / KVBLK;    // 32
    int k0 = z * SPAN;

    auto issue_k = [&](int kb) {
#pragma unroll
        for (int c = 0; c < 4; c++) {
            int seg = wv * 4 + c;                       // 16 x 1KB segments (32 rows x 512B)
            int r = seg * 2 + (lane >> 5);
            int ch = lane & 31;
            const __hip_bfloat16* src = qbf + ((size_t)b * S_ + kb + r) * E_ + ((ch ^ (r & 7)) * 8);
            __builtin_amdgcn_global_load_lds((const __attribute__((address_space(1))) void*)src,
                                             (__attribute__((address_space(3))) void*)(ktile + seg * 512),
                                             16, 0, 0);
        }
    };
    auto issue_v = [&](int kb, int buf) {
#pragma unroll
        for (int c = 0; c < 4; c++) {
            int seg = wv * 4 + c;                       // 16 x 1KB segments (16 e-rows x 64B each)
            int e = seg * 16 + (lane >> 2);
            int ch = lane & 3;
            const __hip_bfloat16* src = qT + ((size_t)b * E_ + e) * S_ + kb + ((ch ^ ((e >> 1) & 3)) * 8);
            __builtin_amdgcn_global_load_lds((const __attribute__((address_space(1))) void*)src,
                                             (__attribute__((address_space(3))) void*)(&vtile[buf][seg * 512]),
                                             16, 0, 0);
        }
    };

    // prologue: tile 0
    issue_k(k0);
    issue_v(k0, 0);
    asm volatile("s_waitcnt vmcnt(0)" ::: "memory");
    __syncthreads();

    for (int kt = 0; kt < NT; kt++) {
        int vcur = kt & 1;
        // ---- QK^T: this wave's kv-half [eh*16, eh*16+16) ----
        f32x4 s0 = (f32x4){0.f,0.f,0.f,0.f}, s1 = (f32x4){0.f,0.f,0.f,0.f};
#pragma unroll
        for (int kk = 0; kk < 8; kk++) {
            bf16x8 bk = *(const bf16x8*)&ktile[(eh * 16 + r16) * 256 + (((kk * 4 + kg) ^ (r16 & 7)) * 8)];
            s0 = MFMA16(aq[0][kk], bk, s0);
            s1 = MFMA16(aq[1][kk], bk, s1);
        }
#pragma unroll
        for (int i = 0; i < 4; i++) {
            float p0 = __expf(fmaf(s0[i], SCALE, -44.0f));
            float p1 = __expf(fmaf(s1[i], SCALE, -44.0f));
            plds[rg][kg * 4 + i][eh * 16 + r16]      = (__bf16)p0;
            plds[rg][16 + kg * 4 + i][eh * 16 + r16] = (__bf16)p1;
            lrow0[i] += p0;
            lrow1[i] += p1;
        }
        __syncthreads();                         // B2: P complete; ktile/vtile[vcur^1] reads done
        bool more = (kt + 1 < NT);
        if (more) {                              // async into ktile + vtile[vcur^1]; lands under PV
            int kn = k0 + (kt + 1) * KVBLK;
            issue_k(kn);
            issue_v(kn, vcur ^ 1);
        }
        // ---- PV ----
        bf16x8 pa0 = *(const bf16x8*)&plds[rg][r16][kg * 8];
        bf16x8 pa1 = *(const bf16x8*)&plds[rg][16 + r16][kg * 8];
#pragma unroll
        for (int cf = 0; cf < 8; cf++) {
            int vrow = ebase + cf * 16 + r16;
            bf16x8 bv = *(const bf16x8*)&vtile[vcur][vrow * KVBLK + ((kg ^ ((vrow >> 1) & 3)) * 8)];
            acc0[cf] = MFMA16(pa0, bv, acc0[cf]);
            acc1[cf] = MFMA16(pa1, bv, acc1[cf]);
        }
        if (more) {
            asm volatile("s_waitcnt vmcnt(0)" ::: "memory");
            __syncthreads();                     // B1: all waves' loads landed
        }
    }

    // ---- epilogue: l totals then partial writes (bf16) ----
#pragma unroll
    for (int i = 0; i < 4; i++) {
#pragma unroll
        for (int m = 1; m <= 8; m <<= 1) {
            lrow0[i] += __shfl_xor(lrow0[i], m);
            lrow1[i] += __shfl_xor(lrow1[i], m);
        }
    }
    if (r16 == 0) {
#pragma unroll
        for (int i = 0; i < 4; i++) {
            redl[rg][kg * 4 + i][eh]      = lrow0[i];
            redl[rg][16 + kg * 4 + i][eh] = lrow1[i];
        }
    }
    __syncthreads();
    size_t prow0 = (size_t)z * BS_ + (size_t)b * S_ + qrow0;
    if (eh == 0 && r16 == 0) {
#pragma unroll
        for (int i = 0; i < 4; i++) {
            int q = kg * 4 + i;
            pl[prow0 + q]      = redl[rg][q][0] + redl[rg][q][1];
            pl[prow0 + 16 + q] = redl[rg][16 + q][0] + redl[rg][16 + q][1];
        }
    }
#pragma unroll
    for (int i = 0; i < 4; i++) {
#pragma unroll
        for (int cf = 0; cf < 8; cf++) {
            pacc[(prow0 + kg * 4 + i) * E_ + ebase + cf * 16 + r16]      = (__bf16)acc0[cf][i];
            pacc[(prow0 + 16 + kg * 4 + i) * E_ + ebase + cf * 16 + r16] = (__bf16)acc1[cf][i];
        }
    }
}

// ---------------- fused merge (2 bf16 partials) + residual + layernorm (bf16 x) ----------------
__global__ __launch_bounds__(256) void k_aln(const __bf16* __restrict__ pacc,
                                             const float* __restrict__ pl,
                                             __bf16* __restrict__ x,
                                             const float* __restrict__ g,
                                             const float* __restrict__ bb) {
    int wv = threadIdx.x >> 6, lane = threadIdx.x & 63;
    size_t row = (size_t)blockIdx.x * 4 + wv;
    float inv = 1.0f / (pl[row] + pl[BS_ + row]);
    bf16x4 a0 = ((const bf16x4*)(pacc + row * E_))[lane];
    bf16x4 a1 = ((const bf16x4*)(pacc + (size_t)BS_ * E_ + row * E_))[lane];
    bf16x4 xv = ((const bf16x4*)(x + row * E_))[lane];
    f32x4 v;
    float s = 0.f, sq = 0.f;
#pragma unroll
    for (int j = 0; j < 4; j++) {
        v[j] = (float)xv[j] + ((float)a0[j] + (float)a1[j]) * inv;
        s += v[j]; sq += v[j] * v[j];
    }
#pragma unroll
    for (int m = 1; m <= 32; m <<= 1) { s += __shfl_xor(s, m); sq += __shfl_xor(sq, m); }
    float mean = s * (1.f / E_);
    float var = sq * (1.f / E_) - mean * mean;
    float rstd = rsqrtf(var + 1e-5f);
    f32x4 gv = ((const f32x4*)g)[lane];
    f32x4 bv = ((const f32x4*)bb)[lane];
    bf16x4 o;
#pragma unroll
    for (int j = 0; j < 4; j++) o[j] = (__bf16)((v[j] - mean) * rstd * gv[j] + bv[j]);
    ((bf16x4*)(x + row * E_))[lane] = o;
}

// ---------------- W2 transpose to bf16 (tiled, all 4 layers in z) ----------------
__global__ __launch_bounds__(256) void k_w2t(const float* __restrict__ W2,
                                             __hip_bfloat16* __restrict__ w2t) {
    __shared__ __align__(16) __bf16 tile[64][72];
    int k0 = blockIdx.x * 64, e0 = blockIdx.y * 64, l = blockIdx.z;
    const float* W2l = W2 + (size_t)l * FF_ * E_;
    __hip_bfloat16* w2tl = w2t + (size_t)l * E_ * FF_;
    int tid = threadIdx.x;
#pragma unroll
    for (int half = 0; half < 2; half++) {
        int r  = half * 32 + (tid >> 3);      // k row
        int c8 = (tid & 7) * 8;               // e offset
        f32x4 v0 = *(const f32x4*)(W2l + (size_t)(k0 + r) * E_ + e0 + c8);
        f32x4 v1 = *(const f32x4*)(W2l + (size_t)(k0 + r) * E_ + e0 + c8 + 4);
#pragma unroll
        for (int j = 0; j < 4; j++) { tile[r][c8 + j] = (__bf16)v0[j]; tile[r][c8 + 4 + j] = (__bf16)v1[j]; }
    }
    __syncthreads();
#pragma unroll
    for (int half = 0; half < 2; half++) {
        int e  = half * 32 + (tid >> 3);
        int k8 = (tid & 7) * 8;
        bf16x8 v;
#pragma unroll
        for (int j = 0; j < 8; j++) v[j] = tile[k8 + j][e];
        *(bf16x8*)(w2tl + (size_t)(e0 + e) * FF_ + k0 + k8) = v;
    }
}

// ---------------- fused FFN: rank-8 h + GEMM + bias + residual + LN (+ q-gen | + mean partials) ----------------
// gen_q=1 (layers 0..2): epilogue writes x and generates q_{l+1} via 8-lane product scans.
// gen_q=0 (layer 3): x store is DEAD (only mean consumed it) — skip it; emit per-block
// column sums of the f32 LN2 output into psum instead (mean fused; k_mean deleted).
__global__ __launch_bounds__(256) void k_ffn(__bf16* __restrict__ x,
                                             const float* __restrict__ theta_l,
                                             const float* __restrict__ W1l,
                                             const float* __restrict__ b1l,
                                             const __hip_bfloat16* __restrict__ w2t,
                                             const float* __restrict__ b2l,
                                             const float* __restrict__ g,
                                             const float* __restrict__ bb,
                                             const float* __restrict__ phi_next,
                                             __bf16* __restrict__ qbf,
                                             __bf16* __restrict__ qT,
                                             float* __restrict__ psum,
                                             int gen_q) {
    __shared__ __align__(16) __bf16 Bld[2][256 * 64];   // [buf][e][k64] linear (global_load_lds dest)
    __shared__ __align__(16) __bf16 Ald[2][32 * 64];    // [buf][r][k64], chunk ^= r&7
    __shared__ float qmld[32][9];
    __shared__ float reds[32][4][2];
    int tid = threadIdx.x;
    int wv = tid >> 6, lane = tid & 63;
    int r16 = lane & 15, kg = lane >> 4;
    int rbase = blockIdx.x * 32;
    int ebQ = wv * 64;
    const int NT = FF_ / 64;   // 16

    {   // qm[r][i] = cos(x[row][i]) * cos(theta[i])
        int r = tid >> 3, i = tid & 7;
        qmld[r][i] = __cosf((float)x[(size_t)(rbase + r) * E_ + i]) * __cosf(theta_l[i]);
    }

    f32x4 w[18];   // W1 chunk (16) + b1 chunk (2), all constant-indexed

    auto issue_B = [&](int kt, int buf) {
#pragma unroll
        for (int s = 0; s < 8; s++) {
            int seg = wv * 8 + s;                       // 32 x 1KB segments
            int e = seg * 8 + (lane >> 3);
            int c = lane & 7;
            const __hip_bfloat16* src = w2t + (size_t)e * FF_ + kt * 64 + ((c ^ (e & 7)) * 8);
            __builtin_amdgcn_global_load_lds((const __attribute__((address_space(1))) void*)src,
                                             (__attribute__((address_space(3))) void*)(&Bld[buf][seg * 512]),
                                             16, 0, 0);
        }
    };
    auto load_W1 = [&](int kt) {
        int c = tid & 7;
        int k = kt * 64 + c * 8;
#pragma unroll
        for (int i = 0; i < 8; i++) {
            w[2 * i]     = *(const f32x4*)(W1l + (size_t)i * FF_ + k);
            w[2 * i + 1] = *(const f32x4*)(W1l + (size_t)i * FF_ + k + 4);
        }
        w[16] = *(const f32x4*)(b1l + k);
        w[17] = *(const f32x4*)(b1l + k + 4);
    };
    auto math_h = [&](int buf) {
        int r = tid >> 3, c = tid & 7;
        f32x4 h0 = w[16], h1 = w[17];
#pragma unroll
        for (int i = 0; i < 8; i++) {
            float qv = qmld[r][i];
#pragma unroll
            for (int j = 0; j < 4; j++) {
                h0[j] = fmaf(qv, w[2 * i][j], h0[j]);
                h1[j] = fmaf(qv, w[2 * i + 1][j], h1[j]);
            }
        }
        bf16x8 hv;
#pragma unroll
        for (int j = 0; j < 4; j++) {
            hv[j]     = (__bf16)fmaxf(h0[j], 0.f);
            hv[4 + j] = (__bf16)fmaxf(h1[j], 0.f);
        }
        *(bf16x8*)&Ald[buf][r * 64 + ((c ^ (r & 7)) * 8)] = hv;
    };

    // prologue
    issue_B(0, 0);
    load_W1(0);
    __syncthreads();          // qmld visible; B(0) drained
    math_h(0);
    __syncthreads();          // Ald[0] visible

    f32x4 acc[2][4];
#pragma unroll
    for (int qs = 0; qs < 2; qs++)
#pragma unroll
        for (int cf = 0; cf < 4; cf++) acc[qs][cf] = (f32x4){0.f, 0.f, 0.f, 0.f};

    for (int kt = 0; kt < NT; kt++) {
        int cur = kt & 1;
        bool more = (kt + 1 < NT);
        if (more) {
            issue_B(kt + 1, cur ^ 1);   // in flight across MFMA phase
            load_W1(kt + 1);            // reg prefetch, consumed after MFMA
        }
        bf16x8 aq[2][2];
#pragma unroll
        for (int qs = 0; qs < 2; qs++)
#pragma unroll
            for (int kk = 0; kk < 2; kk++)
                aq[qs][kk] = *(const bf16x8*)&Ald[cur][(qs * 16 + r16) * 64 + (((kk * 4 + kg) ^ (r16 & 7)) * 8)];
#pragma unroll
        for (int cf = 0; cf < 4; cf++) {
            int e = ebQ + cf * 16 + r16;
#pragma unroll
            for (int kk = 0; kk < 2; kk++) {
                bf16x8 bv = *(const bf16x8*)&Bld[cur][e * 64 + (((kk * 4 + kg) ^ (e & 7)) * 8)];
                acc[0][cf] = MFMA16(aq[0][kk], bv, acc[0][cf]);
                acc[1][cf] = MFMA16(aq[1][kk], bv, acc[1][cf]);
            }
        }
        if (more) {
            math_h(cur ^ 1);            // W1 regs already resident
            __syncthreads();            // drains B(kt+1) + Ald writes; guards buf reuse
        }
    }

    // epilogue: bias + residual + layernorm
    float sA[2][4] = {{0.f,0.f,0.f,0.f},{0.f,0.f,0.f,0.f}};
    float sQ[2][4] = {{0.f,0.f,0.f,0.f},{0.f,0.f,0.f,0.f}};
#pragma unroll
    for (int qs = 0; qs < 2; qs++)
#pragma unroll
        for (int cf = 0; cf < 4; cf++) {
            int e = ebQ + cf * 16 + r16;
            float b2v = b2l[e];
#pragma unroll
            for (int i = 0; i < 4; i++) {
                size_t orow = (size_t)rbase + qs * 16 + kg * 4 + i;
                float t = acc[qs][cf][i] + b2v + (float)x[orow * E_ + e];
                acc[qs][cf][i] = t;
                sA[qs][i] += t; sQ[qs][i] += t * t;
            }
        }
#pragma unroll
    for (int qs = 0; qs < 2; qs++)
#pragma unroll
        for (int i = 0; i < 4; i++) {
#pragma unroll
            for (int m = 1; m <= 8; m <<= 1) {
                sA[qs][i] += __shfl_xor(sA[qs][i], m);
                sQ[qs][i] += __shfl_xor(sQ[qs][i], m);
            }
        }
    if (r16 == 0) {
#pragma unroll
        for (int qs = 0; qs < 2; qs++)
#pragma unroll
            for (int i = 0; i < 4; i++) {
                int row = qs * 16 + kg * 4 + i;
                reds[row][wv][0] = sA[qs][i];
                reds[row][wv][1] = sQ[qs][i];
            }
    }
    __syncthreads();
    float mean[2][4], rstd[2][4];
#pragma unroll
    for (int qs = 0; qs < 2; qs++)
#pragma unroll
        for (int i = 0; i < 4; i++) {
            int row = qs * 16 + kg * 4 + i;
            float S = reds[row][0][0] + reds[row][1][0] + reds[row][2][0] + reds[row][3][0];
            float Q = reds[row][0][1] + reds[row][1][1] + reds[row][2][1] + reds[row][3][1];
            mean[qs][i] = S * (1.f / E_);
            float var = Q * (1.f / E_) - mean[qs][i] * mean[qs][i];
            rstd[qs][i] = rsqrtf(var + 1e-5f);
        }
    // final x1 (keep in acc); store x only when a next layer exists
#pragma unroll
    for (int qs = 0; qs < 2; qs++)
#pragma unroll
        for (int cf = 0; cf < 4; cf++) {
            int e = ebQ + cf * 16 + r16;
            float gv = g[e], bv = bb[e];
#pragma unroll
            for (int i = 0; i < 4; i++) {
                size_t orow = (size_t)rbase + qs * 16 + kg * 4 + i;
                float xn = (acc[qs][cf][i] - mean[qs][i]) * rstd[qs][i] * gv + bv;
                acc[qs][cf][i] = xn;
                if (gen_q) x[orow * E_ + e] = (__bf16)xn;
            }
        }
    if (gen_q) {
        // q-gen for next layer: per 8-lane head group product scans (no division)
        int bq = rbase / S_;
        int trow0 = rbase % S_;
        float ph = phi_next[r16 & 7];
        int hp = r16 & 7;
#pragma unroll
        for (int qs = 0; qs < 2; qs++)
#pragma unroll
            for (int cf = 0; cf < 4; cf++) {
                int e = ebQ + cf * 16 + r16;
#pragma unroll
                for (int i = 0; i < 4; i++) {
                    float c = __cosf(acc[qs][cf][i] + ph);
                    float scan = c;                         // incl prefix prod of c
                    float cp = (hp == 0) ? 1.f : c;         // same with c0 := 1
#pragma unroll
                    for (int d = 1; d <= 4; d <<= 1) {
                        float t1 = __shfl_up(scan, d, 8);
                        float t2 = __shfl_up(cp, d, 8);
                        if (hp >= d) { scan *= t1; cp *= t2; }
                    }
                    float q0 = __shfl(cp, 7, 8);            // prod c1..c7
                    float qv = (hp == 0) ? q0 : scan;
                    int trow = trow0 + qs * 16 + kg * 4 + i;
                    __bf16 qb = (__bf16)qv;
                    qbf[((size_t)bq * S_ + trow) * E_ + e] = qb;
                    qT[((size_t)bq * E_ + e) * S_ + trow]  = qb;
                }
            }
    } else {
        // last layer: per-block column sums of f32 LN2 output -> psum (mean fused)
#pragma unroll
        for (int cf = 0; cf < 4; cf++) {
            int e = ebQ + cf * 16 + r16;
            float s = 0.f;
#pragma unroll
            for (int qs = 0; qs < 2; qs++)
#pragma unroll
                for (int i = 0; i < 4; i++) s += acc[qs][cf][i];
            s += __shfl_xor(s, 16);
            s += __shfl_xor(s, 32);          // fold 4 kg-groups: full 32-row column sum
            if (kg == 0) psum[(size_t)blockIdx.x * E_ + e] = s;
        }
    }
}

// ---------------- final mean reduce (64 block-partials per batch) + nothing else ----------------
__global__ __launch_bounds__(256) void k_mean2(const float* __restrict__ psum, float* __restrict__ xmean) {
    int b = blockIdx.x, e = threadIdx.x;     // 8 blocks x 256 threads
    float s = 0.f;
    for (int c = 0; c < 64; c++) s += psum[((size_t)(b * 64 + c)) * E_ + e];
    xmean[b * E_ + e] = s * (1.f / S_);
}

// ---------------- classifier ----------------
__global__ __launch_bounds__(128) void k_cls(const float* __restrict__ xmean,
                                             const float* __restrict__ Wc,
                                             const float* __restrict__ bc,
                                             float* __restrict__ outp) {
    int t = threadIdx.x;
    if (t >= B_ * NC_) return;
    int b = t / NC_, c = t % NC_;
    float s = bc[c];
    for (int e = 0; e < E_; e++) s += xmean[b * E_ + e] * Wc[e * NC_ + c];
    outp[t] = s;
}

extern "C" void kernel_launch(void* const* d_in, const int* in_sizes, int n_in,
                              void* d_out, int out_size, void* d_ws, size_t ws_size,
                              hipStream_t stream) {
    (void)in_sizes; (void)n_in; (void)out_size; (void)ws_size;
    const int*   tokens = (const int*)d_in[0];
    const float* emb    = (const float*)d_in[1];
    const float* phi    = (const float*)d_in[2];
    const float* theta  = (const float*)d_in[3];
    const float* W1     = (const float*)d_in[4];
    const float* b1     = (const float*)d_in[5];
    const float* W2     = (const float*)d_in[6];
    const float* b2     = (const float*)d_in[7];
    const float* g1     = (const float*)d_in[8];
    const float* beta1  = (const float*)d_in[9];
    const float* g2     = (const float*)d_in[10];
    const float* beta2  = (const float*)d_in[11];
    const float* Wc     = (const float*)d_in[12];
    const float* bc     = (const float*)d_in[13];
    float* outp = (float*)d_out;

    // workspace layout (bf16 residual stream; NSPLIT=2; w2t holds all 4 layers; pacc bf16)
    __bf16* xbuf = (__bf16*)d_ws;                                      // BS_*E_ bf16
    __hip_bfloat16* qbf = (__hip_bfloat16*)(xbuf + (size_t)BS_ * E_);  // BS_*E_ bf16
    __hip_bfloat16* qT  = qbf + (size_t)BS_ * E_;                      // BS_*E_ bf16
    __hip_bfloat16* w2t = qT + (size_t)BS_ * E_;                       // 4*E_*FF_ bf16
    float* psum  = (float*)(w2t + (size_t)4 * E_ * FF_);               // 512*E_ f32 (block partials)
    float* xmean = psum + (size_t)512 * E_;                            // B_*E_ f32
    float* pl    = xmean + B_ * E_;                                    // NSPLIT*BS_ f32
    __bf16* pacc = (__bf16*)(pl + (size_t)NSPLIT * BS_);               // NSPLIT*BS_*E_ bf16

    k_w2t<<<dim3(FF_ / 64, E_ / 64, 4), 256, 0, stream>>>(W2, w2t);
    // fused embed + PE + layer-0 q; layers 1..3 get q from k_ffn's fused epilogue
    k_embqt<<<dim3(S_ / 64, E_ / 64, B_), 256, 0, stream>>>(tokens, emb, phi,
                                                            xbuf, (__bf16*)qbf, (__bf16*)qT);

    for (int l = 0; l < 4; l++) {
        k_attn<<<(S_ / 64) * B_ * NSPLIT, 256, 0, stream>>>(qbf, qT, pacc, pl);
        k_aln<<<BS_ / 4, 256, 0, stream>>>(pacc, pl, xbuf, g1 + l * E_, beta1 + l * E_);
        int gen_q = (l < 3) ? 1 : 0;
        const float* phn = phi + (size_t)(gen_q ? (l + 1) : 0) * NQ_;
        k_ffn<<<BS_ / 32, 256, 0, stream>>>(xbuf, theta + l * NQ_,
                                            W1 + (size_t)l * NQ_ * FF_, b1 + (size_t)l * FF_,
                                            w2t + (size_t)l * E_ * FF_, b2 + (size_t)l * E_,
                                            g2 + l * E_, beta2 + l * E_,
                                            phn, (__bf16*)qbf, (__bf16*)qT, psum, gen_q);
    }

    k_mean2<<<8, 256, 0, stream>>>(psum, xmean);
    k_cls<<<1, 128, 0, stream>>>(xmean, Wc, bc, outp);
}